// Round 2
// baseline (1902.945 us; speedup 1.0000x reference)
//
#include <hip/hip_runtime.h>
#include <hip/hip_bf16.h>

// AngleOrientedConv: per space k (S=4):
//   a  = feat @ W[k][:128,:]              [N,128]
//   bp = feat @ W[k][128:,:] + b[k]       [N,128]
//   e_edge = sum_j tanh(a[src][j] + bp[dst][j]) * w[k][j]
//   segment softmax over dst, out[:, k*128:(k+1)*128] = sum alpha * feat[src]
//
// Strategy: per-node projection (13 GFLOP instead of 210), device-built CSR
// over dst so softmax + weighted sum run atomic-free per node.
// NOTE: index inputs are int32 (harness passes integers as const int*).

#define F 128

__device__ __forceinline__ float fast_tanh(float x) {
    float cx = fminf(fmaxf(x, -15.f), 15.f);
    float t = __expf(2.f * cx);
    return (t - 1.f) / (t + 1.f);
}

// ---------------- proj: a = feat@Wtop, bp = feat@Wbot + b ----------------
// block: 256 threads, 64 nodes per block.
// thread t: mat = t>>7 (0->a, 1->bp), ng = (t>>6)&1 (row half), cp = t&63 (col pair)
__global__ __launch_bounds__(256) void proj_kernel(
    const float* __restrict__ feat, const float* __restrict__ W,
    const float* __restrict__ bvec, float* __restrict__ a,
    float* __restrict__ bp, int N)
{
    __shared__ float sf[64 * 128];  // [r][i], row-major
    const int t = threadIdx.x;
    const int n0 = blockIdx.x * 64;

    // load 64x128 feat tile, float4-coalesced, conflict-free LDS writes
    #pragma unroll
    for (int p = 0; p < 8; ++p) {
        int idx4 = p * 256 + t;          // float4 index
        int r = idx4 >> 5;               // 32 float4 per row
        int ic = (idx4 & 31) * 4;
        int node = n0 + r;
        float4 v = make_float4(0.f, 0.f, 0.f, 0.f);
        if (node < N) v = *(const float4*)(feat + (size_t)node * F + ic);
        *(float4*)(sf + r * F + ic) = v;
    }
    __syncthreads();

    const int mat = t >> 7;
    const int ng  = (t >> 6) & 1;
    const int cp  = t & 63;
    const int c0  = cp * 2;
    const float* Wb = W + (size_t)(mat * F) * F;  // rows mat*128..+127

    float acc0[32], acc1[32];
    #pragma unroll
    for (int r = 0; r < 32; ++r) { acc0[r] = 0.f; acc1[r] = 0.f; }

    for (int i0 = 0; i0 < F; i0 += 4) {
        float2 wv0 = *(const float2*)(Wb + (size_t)(i0 + 0) * F + c0);
        float2 wv1 = *(const float2*)(Wb + (size_t)(i0 + 1) * F + c0);
        float2 wv2 = *(const float2*)(Wb + (size_t)(i0 + 2) * F + c0);
        float2 wv3 = *(const float2*)(Wb + (size_t)(i0 + 3) * F + c0);
        const float* sp = sf + (ng * 32) * F + i0;
        #pragma unroll
        for (int r = 0; r < 32; ++r) {
            float4 v = *(const float4*)(sp + r * F);
            acc0[r] += v.x * wv0.x + v.y * wv1.x + v.z * wv2.x + v.w * wv3.x;
            acc1[r] += v.x * wv0.y + v.y * wv1.y + v.z * wv2.y + v.w * wv3.y;
        }
    }

    float2 bw = make_float2(0.f, 0.f);
    if (mat == 1) bw = *(const float2*)(bvec + c0);
    float* dstp = mat ? bp : a;
    #pragma unroll
    for (int r = 0; r < 32; ++r) {
        int node = n0 + ng * 32 + r;
        if (node < N) {
            float2 o = make_float2(acc0[r] + bw.x, acc1[r] + bw.y);
            *(float2*)(dstp + (size_t)node * F + c0) = o;
        }
    }
}

// ---------------- count incoming edges per dst ----------------
__global__ __launch_bounds__(256) void count_kernel(
    const int* __restrict__ dst, int* __restrict__ cnt, int E)
{
    int e = blockIdx.x * 256 + threadIdx.x;
    if (e < E) atomicAdd(&cnt[dst[e]], 1);
}

// ---------------- single-block exclusive scan -> row_off; cnt becomes cursor ----------------
__global__ __launch_bounds__(1024) void scan_kernel(
    int* __restrict__ cnt, int* __restrict__ row_off, int N)
{
    __shared__ int part[1024];
    const int t = threadIdx.x;
    const int chunk = (N + 1023) / 1024;
    const int b = t * chunk;
    const int e_ = min(N, b + chunk);
    int sum = 0;
    for (int i = b; i < e_; ++i) sum += cnt[i];
    part[t] = sum;
    __syncthreads();
    for (int off = 1; off < 1024; off <<= 1) {
        int v = (t >= off) ? part[t - off] : 0;
        __syncthreads();
        part[t] += v;
        __syncthreads();
    }
    int excl = (t == 0) ? 0 : part[t - 1];
    for (int i = b; i < e_; ++i) {
        int c = cnt[i];
        row_off[i] = excl;
        cnt[i] = excl;   // cursor for fill pass
        excl += c;
    }
    if (t == 1023) row_off[N] = excl;
}

// ---------------- edge pass: compute e, write into CSR slots ----------------
// wave (64 lanes) per edge, 2 features per lane
__global__ __launch_bounds__(256) void edge_e_kernel(
    const float* __restrict__ a, const float* __restrict__ bp,
    const float* __restrict__ w, const int* __restrict__ src,
    const int* __restrict__ dst, int* __restrict__ cursor,
    float* __restrict__ e_csr, int* __restrict__ src_csr, int E)
{
    int gid = blockIdx.x * 256 + threadIdx.x;
    int e = gid >> 6;
    int lane = threadIdx.x & 63;
    if (e >= E) return;
    int s_ = src[e];
    int d_ = dst[e];
    float2 av = *(const float2*)(a  + (size_t)s_ * F + 2 * lane);
    float2 bv = *(const float2*)(bp + (size_t)d_ * F + 2 * lane);
    float2 wv = *(const float2*)(w + 2 * lane);
    float p = fast_tanh(av.x + bv.x) * wv.x + fast_tanh(av.y + bv.y) * wv.y;
    #pragma unroll
    for (int off = 32; off; off >>= 1) p += __shfl_xor(p, off);
    if (lane == 0) {
        int pos = atomicAdd(&cursor[d_], 1);
        e_csr[pos] = p;
        src_csr[pos] = s_;
    }
}

// ---------------- node pass: softmax + weighted feat sum, atomic-free ----------------
// wave per node; 2 output features per lane
__global__ __launch_bounds__(256) void node_kernel(
    const float* __restrict__ feat, const float* __restrict__ e_csr,
    const int* __restrict__ src_csr, const int* __restrict__ row_off,
    float* __restrict__ out, int N, int S, int k)
{
    int node = blockIdx.x * 4 + (threadIdx.x >> 6);
    int lane = threadIdx.x & 63;
    if (node >= N) return;
    int beg = row_off[node];
    int cnt = row_off[node + 1] - beg;
    float* outp = out + (size_t)node * (S * F) + k * F;
    if (cnt == 0) {
        *(float2*)(outp + 2 * lane) = make_float2(0.f, 0.f);
        return;
    }
    // phase 1: max
    float m = -INFINITY;
    for (int base = 0; base < cnt; base += 64) {
        int idx = base + lane;
        float v = (idx < cnt) ? e_csr[beg + idx] : -INFINITY;
        m = fmaxf(m, v);
    }
    #pragma unroll
    for (int off = 32; off; off >>= 1) m = fmaxf(m, __shfl_xor(m, off));
    // phase 2: exp-sum and weighted feature accumulation
    float ssum = 0.f, acc0 = 0.f, acc1 = 0.f;
    for (int base = 0; base < cnt; base += 64) {
        int idx = base + lane;
        int valid = min(64, cnt - base);
        float ex = 0.f;
        int sv = 0;
        if (idx < cnt) {
            ex = __expf(e_csr[beg + idx] - m);
            sv = src_csr[beg + idx];
        }
        float exs = ex;
        #pragma unroll
        for (int off = 32; off; off >>= 1) exs += __shfl_xor(exs, off);
        ssum += exs;
        for (int je = 0; je < valid; ++je) {
            float exj = __shfl(ex, je);
            int sj = __shfl(sv, je);
            float2 f = *(const float2*)(feat + (size_t)sj * F + 2 * lane);
            acc0 += exj * f.x;
            acc1 += exj * f.y;
        }
    }
    float inv = 1.f / ssum;
    *(float2*)(outp + 2 * lane) = make_float2(acc0 * inv, acc1 * inv);
}

extern "C" void kernel_launch(void* const* d_in, const int* in_sizes, int n_in,
                              void* d_out, int out_size, void* d_ws, size_t ws_size,
                              hipStream_t stream) {
    const float* feat = (const float*)d_in[0];
    const int*   src  = (const int*)d_in[1];
    const int*   dst  = (const int*)d_in[2];
    const float* W    = (const float*)d_in[3];
    const float* bvec = (const float*)d_in[4];
    const float* wout = (const float*)d_in[5];
    float* out = (float*)d_out;

    const int N = in_sizes[0] / F;
    const int S = in_sizes[3] / (2 * F * F);
    const int E = in_sizes[1] / S;

    // workspace layout (fp32 units)
    float* a     = (float*)d_ws;                 // N*F
    float* bp    = a + (size_t)N * F;            // N*F
    float* e_csr = bp + (size_t)N * F;           // E
    int*   src_csr = (int*)(e_csr + E);          // E
    int*   row_off = src_csr + E;                // N+1
    int*   cnt     = row_off + N + 1;            // N

    const int proj_blocks  = (N + 63) / 64;
    const int count_blocks = (E + 255) / 256;
    const int edge_blocks  = (E + 3) / 4;        // 4 waves/block, wave per edge
    const int node_blocks  = (N + 3) / 4;

    for (int k = 0; k < S; ++k) {
        const float* Wk   = W + (size_t)k * 2 * F * F;
        const float* bk   = bvec + (size_t)k * F;
        const float* wk   = wout + (size_t)k * F;
        const int*   srck = src + (size_t)k * E;
        const int*   dstk = dst + (size_t)k * E;

        proj_kernel<<<proj_blocks, 256, 0, stream>>>(feat, Wk, bk, a, bp, N);
        hipMemsetAsync(cnt, 0, (size_t)N * sizeof(int), stream);
        count_kernel<<<count_blocks, 256, 0, stream>>>(dstk, cnt, E);
        scan_kernel<<<1, 1024, 0, stream>>>(cnt, row_off, N);
        edge_e_kernel<<<edge_blocks, 256, 0, stream>>>(a, bp, wk, srck, dstk,
                                                       cnt, e_csr, src_csr, E);
        node_kernel<<<node_blocks, 256, 0, stream>>>(feat, e_csr, src_csr,
                                                     row_off, out, N, S, k);
    }
}

// Round 3
// 1669.848 us; speedup vs baseline: 1.1396x; 1.1396x over previous
//
#include <hip/hip_runtime.h>
#include <hip/hip_bf16.h>

// AngleOrientedConv: per space k (S=4):
//   a  = feat @ W[k][:128,:]              [N,128]
//   bp = feat @ W[k][128:,:] + b[k]       [N,128]
//   e  = sum_j tanh(a[src][j] + bp[dst][j]) * w[k][j]
//   segment softmax over dst; out[:, k*128:(k+1)*128] = sum alpha * feat[src]
//
// Round 3: bf16 staging of feat/a/bp (halves gather bytes), CSR-ordered FUSED
// edge+node kernel (bp[d], w held in registers per node; e in per-wave LDS;
// softmax + weighted feat gather in same wave). f32 accumulation throughout.

#define F 128
#define CAP 256  // per-wave LDS e-buffer entries (degree fallback -> global spill)

__device__ __forceinline__ unsigned f2bf(float x) {  // round-to-nearest-even
    unsigned u = __float_as_uint(x);
    unsigned r = ((u >> 16) & 1u) + 0x7fffu;
    return (u + r) >> 16;
}
__device__ __forceinline__ float bf_lo(unsigned v) { return __uint_as_float(v << 16); }
__device__ __forceinline__ float bf_hi(unsigned v) { return __uint_as_float(v & 0xffff0000u); }

__device__ __forceinline__ float fast_tanh(float x) {
    // 1 - 2/(e^{2x}+1): saturates correctly at +/-inf, no clamp needed
    float ex = __expf(2.f * x);
    return 1.f - 2.f * __builtin_amdgcn_rcpf(ex + 1.f);
}

// ---------------- feat -> bf16 copy (once per call) ----------------
__global__ __launch_bounds__(256) void cvt_feat_kernel(
    const float* __restrict__ feat, unsigned* __restrict__ feat16, int n4)
{
    for (int i = blockIdx.x * 256 + threadIdx.x; i < n4; i += gridDim.x * 256) {
        float4 v = *(const float4*)(feat + (size_t)i * 4);
        unsigned lo = f2bf(v.x) | (f2bf(v.y) << 16);
        unsigned hi = f2bf(v.z) | (f2bf(v.w) << 16);
        *(uint2*)(feat16 + (size_t)i * 2) = make_uint2(lo, hi);
    }
}

// ---------------- proj: a16 = bf16(feat@Wtop), bp16 = bf16(feat@Wbot + b) ----
__global__ __launch_bounds__(256) void proj_kernel(
    const float* __restrict__ feat, const float* __restrict__ W,
    const float* __restrict__ bvec, unsigned* __restrict__ a16,
    unsigned* __restrict__ bp16, int N)
{
    __shared__ float sf[64 * 128];
    const int t = threadIdx.x;
    const int n0 = blockIdx.x * 64;

    #pragma unroll
    for (int p = 0; p < 8; ++p) {
        int idx4 = p * 256 + t;
        int r = idx4 >> 5;
        int ic = (idx4 & 31) * 4;
        int node = n0 + r;
        float4 v = make_float4(0.f, 0.f, 0.f, 0.f);
        if (node < N) v = *(const float4*)(feat + (size_t)node * F + ic);
        *(float4*)(sf + r * F + ic) = v;
    }
    __syncthreads();

    const int mat = t >> 7;
    const int ng  = (t >> 6) & 1;
    const int cp  = t & 63;
    const int c0  = cp * 2;
    const float* Wb = W + (size_t)(mat * F) * F;

    float acc0[32], acc1[32];
    #pragma unroll
    for (int r = 0; r < 32; ++r) { acc0[r] = 0.f; acc1[r] = 0.f; }

    for (int i0 = 0; i0 < F; i0 += 4) {
        float2 wv0 = *(const float2*)(Wb + (size_t)(i0 + 0) * F + c0);
        float2 wv1 = *(const float2*)(Wb + (size_t)(i0 + 1) * F + c0);
        float2 wv2 = *(const float2*)(Wb + (size_t)(i0 + 2) * F + c0);
        float2 wv3 = *(const float2*)(Wb + (size_t)(i0 + 3) * F + c0);
        const float* sp = sf + (ng * 32) * F + i0;
        #pragma unroll
        for (int r = 0; r < 32; ++r) {
            float4 v = *(const float4*)(sp + r * F);
            acc0[r] += v.x * wv0.x + v.y * wv1.x + v.z * wv2.x + v.w * wv3.x;
            acc1[r] += v.x * wv0.y + v.y * wv1.y + v.z * wv2.y + v.w * wv3.y;
        }
    }

    float2 bw = make_float2(0.f, 0.f);
    if (mat == 1) bw = *(const float2*)(bvec + c0);
    unsigned* dstp = mat ? bp16 : a16;
    #pragma unroll
    for (int r = 0; r < 32; ++r) {
        int node = n0 + ng * 32 + r;
        if (node < N) {
            unsigned o = f2bf(acc0[r] + bw.x) | (f2bf(acc1[r] + bw.y) << 16);
            dstp[(size_t)node * 64 + cp] = o;
        }
    }
}

// ---------------- count incoming edges per dst ----------------
__global__ __launch_bounds__(256) void count_kernel(
    const int* __restrict__ dst, int* __restrict__ cnt, int E)
{
    int e = blockIdx.x * 256 + threadIdx.x;
    if (e < E) atomicAdd(&cnt[dst[e]], 1);
}

// ---------------- single-block exclusive scan -> row_off; cnt becomes cursor --
__global__ __launch_bounds__(1024) void scan_kernel(
    int* __restrict__ cnt, int* __restrict__ row_off, int N)
{
    __shared__ int part[1024];
    const int t = threadIdx.x;
    const int chunk = (N + 1023) / 1024;
    const int b = t * chunk;
    const int e_ = min(N, b + chunk);
    int sum = 0;
    for (int i = b; i < e_; ++i) sum += cnt[i];
    part[t] = sum;
    __syncthreads();
    for (int off = 1; off < 1024; off <<= 1) {
        int v = (t >= off) ? part[t - off] : 0;
        __syncthreads();
        part[t] += v;
        __syncthreads();
    }
    int excl = (t == 0) ? 0 : part[t - 1];
    for (int i = b; i < e_; ++i) {
        int c = cnt[i];
        row_off[i] = excl;
        cnt[i] = excl;   // becomes cursor for fill pass
        excl += c;
    }
    if (t == 1023) row_off[N] = excl;
}

// ---------------- fill: src_csr in dst-CSR order ----------------
__global__ __launch_bounds__(256) void fill_kernel(
    const int* __restrict__ src, const int* __restrict__ dst,
    int* __restrict__ cursor, int* __restrict__ src_csr, int E)
{
    int e = blockIdx.x * 256 + threadIdx.x;
    if (e < E) {
        int pos = atomicAdd(&cursor[dst[e]], 1);
        src_csr[pos] = src[e];
    }
}

// ---------------- fused edge-attention + softmax + weighted gather ----------
// wave per dst node; 2 features per lane.
__global__ __launch_bounds__(256) void fused_kernel(
    const unsigned* __restrict__ feat16, const unsigned* __restrict__ a16,
    const unsigned* __restrict__ bp16, const float* __restrict__ w,
    const int* __restrict__ src_csr, const int* __restrict__ row_off,
    float* __restrict__ e_spill, float* __restrict__ out, int N, int S, int k)
{
    __shared__ float els[4][CAP];
    const int wslot = threadIdx.x >> 6;
    const int node = blockIdx.x * 4 + wslot;
    const int lane = threadIdx.x & 63;
    if (node >= N) return;

    const int beg = row_off[node];
    const int cnt = row_off[node + 1] - beg;
    float* outp = out + (size_t)node * (S * F) + k * F;
    if (cnt == 0) {
        *(float2*)(outp + 2 * lane) = make_float2(0.f, 0.f);
        return;
    }

    unsigned bpv = bp16[(size_t)node * 64 + lane];
    const float b0 = bf_lo(bpv), b1 = bf_hi(bpv);
    const float2 wv = *(const float2*)(w + 2 * lane);

    // ---- pass 1: e per edge (gather a16[src]), running max ----
    float m = -INFINITY;
    for (int base = 0; base < cnt; base += 64) {
        int idx = base + lane;
        int sv = (idx < cnt) ? src_csr[beg + idx] : 0;
        int valid = min(64, cnt - base);
        for (int je = 0; je < valid; ++je) {
            int sj = __shfl(sv, je);
            unsigned av = a16[(size_t)sj * 64 + lane];
            float p = fast_tanh(bf_lo(av) + b0) * wv.x
                    + fast_tanh(bf_hi(av) + b1) * wv.y;
            #pragma unroll
            for (int off = 32; off; off >>= 1) p += __shfl_xor(p, off);
            m = fmaxf(m, p);
            int pos = base + je;
            if (lane == 0) {
                if (pos < CAP) els[wslot][pos] = p;
                else           e_spill[beg + pos] = p;
            }
        }
    }

    // ---- pass 2: exp-sum + weighted feat16[src] gather ----
    float ssum = 0.f, acc0 = 0.f, acc1 = 0.f;
    for (int base = 0; base < cnt; base += 64) {
        int idx = base + lane;
        float ex = 0.f;
        int sv = 0;
        if (idx < cnt) {
            float ev = (idx < CAP) ? els[wslot][idx] : e_spill[beg + idx];
            ex = __expf(ev - m);
            sv = src_csr[beg + idx];
        }
        ssum += ex;
        int valid = min(64, cnt - base);
        for (int je = 0; je < valid; ++je) {
            float exj = __shfl(ex, je);
            int sj = __shfl(sv, je);
            unsigned fv = feat16[(size_t)sj * 64 + lane];
            acc0 += exj * bf_lo(fv);
            acc1 += exj * bf_hi(fv);
        }
    }
    #pragma unroll
    for (int off = 32; off; off >>= 1) ssum += __shfl_xor(ssum, off);
    float inv = __builtin_amdgcn_rcpf(ssum);
    *(float2*)(outp + 2 * lane) = make_float2(acc0 * inv, acc1 * inv);
}

extern "C" void kernel_launch(void* const* d_in, const int* in_sizes, int n_in,
                              void* d_out, int out_size, void* d_ws, size_t ws_size,
                              hipStream_t stream) {
    const float* feat = (const float*)d_in[0];
    const int*   src  = (const int*)d_in[1];
    const int*   dst  = (const int*)d_in[2];
    const float* W    = (const float*)d_in[3];
    const float* bvec = (const float*)d_in[4];
    const float* wout = (const float*)d_in[5];
    float* out = (float*)d_out;

    const int N = in_sizes[0] / F;
    const int S = in_sizes[3] / (2 * F * F);
    const int E = in_sizes[1] / S;

    // workspace layout
    unsigned* feat16 = (unsigned*)d_ws;               // N*64 uints (12.8MB)
    unsigned* a16    = feat16 + (size_t)N * 64;       // N*64
    unsigned* bp16   = a16 + (size_t)N * 64;          // N*64
    float*    e_spill = (float*)(bp16 + (size_t)N * 64);  // E
    int*      src_csr = (int*)(e_spill + E);          // E
    int*      row_off = src_csr + E;                  // N+1
    int*      cnt     = row_off + N + 1;              // N

    const int n4 = N * F / 4;
    const int proj_blocks  = (N + 63) / 64;
    const int e_blocks     = (E + 255) / 256;
    const int node_blocks  = (N + 3) / 4;

    cvt_feat_kernel<<<2048, 256, 0, stream>>>(feat, feat16, n4);

    for (int k = 0; k < S; ++k) {
        const float* Wk   = W + (size_t)k * 2 * F * F;
        const float* bk   = bvec + (size_t)k * F;
        const float* wk   = wout + (size_t)k * F;
        const int*   srck = src + (size_t)k * E;
        const int*   dstk = dst + (size_t)k * E;

        proj_kernel<<<proj_blocks, 256, 0, stream>>>(feat, Wk, bk, a16, bp16, N);
        hipMemsetAsync(cnt, 0, (size_t)N * sizeof(int), stream);
        count_kernel<<<e_blocks, 256, 0, stream>>>(dstk, cnt, E);
        scan_kernel<<<1, 1024, 0, stream>>>(cnt, row_off, N);
        fill_kernel<<<e_blocks, 256, 0, stream>>>(srck, dstk, cnt, src_csr, E);
        fused_kernel<<<node_blocks, 256, 0, stream>>>(feat16, a16, bp16, wk,
                                                      src_csr, row_off, e_spill,
                                                      out, N, S, k);
    }
}

// Round 4
// 840.295 us; speedup vs baseline: 2.2646x; 1.9872x over previous
//
#include <hip/hip_runtime.h>
#include <hip/hip_bf16.h>

// AngleOrientedConv: per space k (S=4):
//   a  = feat @ W[k][:128,:];  bp = feat @ W[k][128:,:] + b[k]
//   e  = sum_j tanh(a[src][j] + bp[dst][j]) * w[k][j]
//   segment softmax over dst; out[:, k*128:(k+1)*128] = sum alpha * feat[src]
//
// Round 4: batch CSR build + proj + fused across spaces (runtime ws_size
// fallback to per-space), parallel hierarchical scan, and a 16-lane-per-edge
// fused kernel (4 edges in flight per wave, cross-group reduce once per node).

#define F 128
#define CAP 256   // per-wave LDS e-buffer entries; degree > CAP spills to global

__device__ __forceinline__ unsigned f2bf(float x) {  // round-to-nearest-even
    unsigned u = __float_as_uint(x);
    unsigned r = ((u >> 16) & 1u) + 0x7fffu;
    return (u + r) >> 16;
}
__device__ __forceinline__ float bf_lo(unsigned v) { return __uint_as_float(v << 16); }
__device__ __forceinline__ float bf_hi(unsigned v) { return __uint_as_float(v & 0xffff0000u); }

__device__ __forceinline__ float fast_tanh(float x) {
    // 1 - 2/(e^{2x}+1): saturates correctly, no clamp needed
    float ex = __expf(2.f * x);
    return 1.f - 2.f * __builtin_amdgcn_rcpf(ex + 1.f);
}

// ---------------- feat -> bf16 (once) ----------------
__global__ __launch_bounds__(256) void cvt_feat_kernel(
    const float* __restrict__ feat, unsigned* __restrict__ feat16, int n4)
{
    for (int i = blockIdx.x * 256 + threadIdx.x; i < n4; i += gridDim.x * 256) {
        float4 v = *(const float4*)(feat + (size_t)i * 4);
        unsigned lo = f2bf(v.x) | (f2bf(v.y) << 16);
        unsigned hi = f2bf(v.z) | (f2bf(v.w) << 16);
        *(uint2*)(feat16 + (size_t)i * 2) = make_uint2(lo, hi);
    }
}

// ---------------- proj (batched over spaces via blockIdx.y) ----------------
__global__ __launch_bounds__(256) void proj_kernel(
    const float* __restrict__ feat, const float* __restrict__ W,
    const float* __restrict__ bvec, unsigned* __restrict__ a16,
    unsigned* __restrict__ bp16, int N, int k0)
{
    __shared__ float sf[64 * 128];
    const int t = threadIdx.x;
    const int n0 = blockIdx.x * 64;
    const int by = blockIdx.y;
    const int k = k0 + by;

    #pragma unroll
    for (int p = 0; p < 8; ++p) {
        int idx4 = p * 256 + t;
        int r = idx4 >> 5;
        int ic = (idx4 & 31) * 4;
        int node = n0 + r;
        float4 v = make_float4(0.f, 0.f, 0.f, 0.f);
        if (node < N) v = *(const float4*)(feat + (size_t)node * F + ic);
        *(float4*)(sf + r * F + ic) = v;
    }
    __syncthreads();

    const int mat = t >> 7;
    const int ng  = (t >> 6) & 1;
    const int cp  = t & 63;
    const int c0  = cp * 2;
    const float* Wb = W + (size_t)k * 2 * F * F + (size_t)(mat * F) * F;

    float acc0[32], acc1[32];
    #pragma unroll
    for (int r = 0; r < 32; ++r) { acc0[r] = 0.f; acc1[r] = 0.f; }

    for (int i0 = 0; i0 < F; i0 += 4) {
        float2 wv0 = *(const float2*)(Wb + (size_t)(i0 + 0) * F + c0);
        float2 wv1 = *(const float2*)(Wb + (size_t)(i0 + 1) * F + c0);
        float2 wv2 = *(const float2*)(Wb + (size_t)(i0 + 2) * F + c0);
        float2 wv3 = *(const float2*)(Wb + (size_t)(i0 + 3) * F + c0);
        const float* sp = sf + (ng * 32) * F + i0;
        #pragma unroll
        for (int r = 0; r < 32; ++r) {
            float4 v = *(const float4*)(sp + r * F);
            acc0[r] += v.x * wv0.x + v.y * wv1.x + v.z * wv2.x + v.w * wv3.x;
            acc1[r] += v.x * wv0.y + v.y * wv1.y + v.z * wv2.y + v.w * wv3.y;
        }
    }

    float2 bw = make_float2(0.f, 0.f);
    if (mat == 1) bw = *(const float2*)(bvec + (size_t)k * F + c0);
    unsigned* dstp = (mat ? bp16 : a16) + (size_t)by * N * 64;
    #pragma unroll
    for (int r = 0; r < 32; ++r) {
        int node = n0 + ng * 32 + r;
        if (node < N) {
            unsigned o = f2bf(acc0[r] + bw.x) | (f2bf(acc1[r] + bw.y) << 16);
            dstp[(size_t)node * 64 + cp] = o;
        }
    }
}

// ---------------- CSR build, batched over all spaces ----------------
__global__ __launch_bounds__(256) void count_all_kernel(
    const int* __restrict__ dst, int* __restrict__ cnt, int E, int SE, int N)
{
    int e = blockIdx.x * 256 + threadIdx.x;
    if (e < SE) {
        int s = e / E;
        atomicAdd(&cnt[(size_t)s * N + dst[e]], 1);
    }
}

__global__ __launch_bounds__(256) void partial_kernel(
    const int* __restrict__ cnt, int* __restrict__ partials, int N, int BPS)
{
    __shared__ int red[256];
    const int s = blockIdx.y, b = blockIdx.x, t = threadIdx.x;
    int i = b * 256 + t;
    red[t] = (i < N) ? cnt[(size_t)s * N + i] : 0;
    __syncthreads();
    #pragma unroll
    for (int off = 128; off; off >>= 1) {
        if (t < off) red[t] += red[t + off];
        __syncthreads();
    }
    if (t == 0) partials[s * BPS + b] = red[0];
}

__global__ __launch_bounds__(1024) void scan_partials_kernel(
    const int* __restrict__ partials, int* __restrict__ scanned,
    int* __restrict__ row_off, int S, int BPS, int N)
{
    __shared__ int buf[1024];
    const int t = threadIdx.x;
    const int total = S * BPS;   // must be <= 1024
    buf[t] = (t < total) ? partials[t] : 0;
    __syncthreads();
    for (int off = 1; off < 1024; off <<= 1) {
        int x = (t >= off) ? buf[t - off] : 0;
        __syncthreads();
        buf[t] += x;
        __syncthreads();
    }
    if (t < total) {
        int s = t / BPS;
        int g_excl = (t == 0) ? 0 : buf[t - 1];
        int base = (s == 0) ? 0 : buf[s * BPS - 1];
        scanned[t] = g_excl - base;
    }
    if (t < S) {
        int end  = buf[(t + 1) * BPS - 1];
        int base = (t == 0) ? 0 : buf[t * BPS - 1];
        row_off[(size_t)t * (N + 1) + N] = end - base;
    }
}

__global__ __launch_bounds__(256) void emit_kernel(
    const int* __restrict__ cnt, const int* __restrict__ scanned,
    int* __restrict__ row_off, int* __restrict__ cursor, int N, int BPS)
{
    __shared__ int buf[256];
    const int s = blockIdx.y, b = blockIdx.x, t = threadIdx.x;
    int i = b * 256 + t;
    int v = (i < N) ? cnt[(size_t)s * N + i] : 0;
    buf[t] = v;
    __syncthreads();
    for (int off = 1; off < 256; off <<= 1) {
        int x = (t >= off) ? buf[t - off] : 0;
        __syncthreads();
        buf[t] += x;
        __syncthreads();
    }
    int row = scanned[s * BPS + b] + buf[t] - v;
    if (i < N) {
        row_off[(size_t)s * (N + 1) + i] = row;
        cursor[(size_t)s * N + i] = row;   // aliases cnt; all reads done above
    }
}

__global__ __launch_bounds__(256) void fill_all_kernel(
    const int* __restrict__ src, const int* __restrict__ dst,
    int* __restrict__ cursor, int* __restrict__ src_csr,
    int E, int SE, int N)
{
    int e = blockIdx.x * 256 + threadIdx.x;
    if (e < SE) {
        int s = e / E;
        int pos = atomicAdd(&cursor[(size_t)s * N + dst[e]], 1);
        src_csr[(size_t)s * E + pos] = src[e];
    }
}

// ---------------- fused attention+softmax+gather: 16 lanes/edge ----------
__global__ __launch_bounds__(256) void fused_kernel(
    const uint4* __restrict__ feat16, const uint4* __restrict__ a16,
    const uint4* __restrict__ bp16, const float* __restrict__ wout,
    const int* __restrict__ src_csr_all, const int* __restrict__ row_off_all,
    float* __restrict__ e_spill, float* __restrict__ out,
    int N, int S, int E, int k0)
{
    __shared__ float els[4][CAP];
    const int by = blockIdx.y;
    const int k = k0 + by;
    const int wslot = threadIdx.x >> 6;
    const int node = blockIdx.x * 4 + wslot;
    const int lane = threadIdx.x & 63;
    const int eg = lane >> 4;     // edge group 0..3
    const int fl = lane & 15;     // feature slot (8 bf16 per lane)
    if (node >= N) return;

    const int* row_off = row_off_all + (size_t)k * (N + 1);
    const int* src_csr = src_csr_all + (size_t)k * E;
    float* spill = e_spill + (size_t)by * E;
    const uint4* a16k  = a16  + (size_t)by * N * 16;
    const uint4* bp16k = bp16 + (size_t)by * N * 16;

    const int beg = row_off[node];
    const int cnt = row_off[node + 1] - beg;
    float* outp = out + (size_t)node * (S * F) + k * F;
    if (cnt == 0) {
        if (eg == 0) {
            *(float4*)(outp + fl * 8)     = make_float4(0.f, 0.f, 0.f, 0.f);
            *(float4*)(outp + fl * 8 + 4) = make_float4(0.f, 0.f, 0.f, 0.f);
        }
        return;
    }

    uint4 bv = bp16k[(size_t)node * 16 + fl];
    const float b0 = bf_lo(bv.x), b1 = bf_hi(bv.x);
    const float b2 = bf_lo(bv.y), b3 = bf_hi(bv.y);
    const float b4 = bf_lo(bv.z), b5 = bf_hi(bv.z);
    const float b6 = bf_lo(bv.w), b7 = bf_hi(bv.w);
    const float4* w4 = (const float4*)(wout + (size_t)k * F);
    const float4 w0 = w4[fl * 2];
    const float4 w1 = w4[fl * 2 + 1];

    // ---- pass 1: e per edge, running max ----
    float m = -INFINITY;
    for (int chunk = 0; chunk < cnt; chunk += 64) {
        int idx = chunk + lane;
        int sv = (idx < cnt) ? src_csr[beg + idx] : 0;
        int cend = min(64, cnt - chunk);
        for (int q = 0; q < cend; q += 4) {
            int my = q + eg;
            int sj = __shfl(sv, my);
            uint4 av = a16k[(size_t)sj * 16 + fl];
            float p = fast_tanh(bf_lo(av.x) + b0) * w0.x
                    + fast_tanh(bf_hi(av.x) + b1) * w0.y
                    + fast_tanh(bf_lo(av.y) + b2) * w0.z
                    + fast_tanh(bf_hi(av.y) + b3) * w0.w
                    + fast_tanh(bf_lo(av.z) + b4) * w1.x
                    + fast_tanh(bf_hi(av.z) + b5) * w1.y
                    + fast_tanh(bf_lo(av.w) + b6) * w1.z
                    + fast_tanh(bf_hi(av.w) + b7) * w1.w;
            p += __shfl_xor(p, 1); p += __shfl_xor(p, 2);
            p += __shfl_xor(p, 4); p += __shfl_xor(p, 8);
            if (my < cend) {
                m = fmaxf(m, p);
                if (fl == 0) {
                    int pos = chunk + my;
                    if (pos < CAP) els[wslot][pos] = p;
                    else           spill[beg + pos] = p;
                }
            }
        }
    }
    m = fmaxf(m, __shfl_xor(m, 16));
    m = fmaxf(m, __shfl_xor(m, 32));

    // ---- pass 2: exp-sum + weighted feat gather ----
    float ssum = 0.f;
    float acc[8] = {0.f, 0.f, 0.f, 0.f, 0.f, 0.f, 0.f, 0.f};
    for (int chunk = 0; chunk < cnt; chunk += 64) {
        int idx = chunk + lane;
        int sv = 0;
        float exl = 0.f;
        if (idx < cnt) {
            sv = src_csr[beg + idx];
            float ev = (idx < CAP) ? els[wslot][idx] : spill[beg + idx];
            exl = __expf(ev - m);
        }
        ssum += exl;
        int cend = min(64, cnt - chunk);
        for (int q = 0; q < cend; q += 4) {
            int my = q + eg;
            int sj = __shfl(sv, my);        // edge's src (0 if inactive)
            float exj = __shfl(exl, my);    // edge's weight (0 if inactive)
            uint4 fv = feat16[(size_t)sj * 16 + fl];
            acc[0] += exj * bf_lo(fv.x); acc[1] += exj * bf_hi(fv.x);
            acc[2] += exj * bf_lo(fv.y); acc[3] += exj * bf_hi(fv.y);
            acc[4] += exj * bf_lo(fv.z); acc[5] += exj * bf_hi(fv.z);
            acc[6] += exj * bf_lo(fv.w); acc[7] += exj * bf_hi(fv.w);
        }
    }
    #pragma unroll
    for (int off = 32; off; off >>= 1) ssum += __shfl_xor(ssum, off);
    #pragma unroll
    for (int j = 0; j < 8; ++j) {
        acc[j] += __shfl_xor(acc[j], 16);
        acc[j] += __shfl_xor(acc[j], 32);
    }
    float inv = __builtin_amdgcn_rcpf(ssum);
    if (eg == 0) {
        *(float4*)(outp + fl * 8) =
            make_float4(acc[0] * inv, acc[1] * inv, acc[2] * inv, acc[3] * inv);
        *(float4*)(outp + fl * 8 + 4) =
            make_float4(acc[4] * inv, acc[5] * inv, acc[6] * inv, acc[7] * inv);
    }
}

extern "C" void kernel_launch(void* const* d_in, const int* in_sizes, int n_in,
                              void* d_out, int out_size, void* d_ws, size_t ws_size,
                              hipStream_t stream) {
    const float* feat = (const float*)d_in[0];
    const int*   src  = (const int*)d_in[1];
    const int*   dst  = (const int*)d_in[2];
    const float* W    = (const float*)d_in[3];
    const float* bvec = (const float*)d_in[4];
    const float* wout = (const float*)d_in[5];
    float* out = (float*)d_out;

    const int N = in_sizes[0] / F;
    const int S = in_sizes[3] / (2 * F * F);
    const int E = in_sizes[1] / S;
    const int SE = S * E;
    const int BPS = (N + 255) / 256;   // scan blocks per space (S*BPS <= 1024)

    // choose batch factor B for a16/bp16/spill buffers based on ws_size
    size_t fixed = (size_t)N * 64 * 4            // feat16
                 + (size_t)SE * 4                // src_csr
                 + (size_t)S * N * 4             // cnt/cursor
                 + (size_t)S * (N + 1) * 4       // row_off
                 + (size_t)S * BPS * 4 * 2;      // partials + scanned
    size_t perB = (size_t)N * 64 * 4 * 2         // a16 + bp16
                + (size_t)E * 4;                 // spill
    const int B = (ws_size >= fixed + perB * (size_t)S + 1024) ? S : 1;

    char* p = (char*)d_ws;
    unsigned* feat16   = (unsigned*)p;  p += (size_t)N * 64 * 4;
    unsigned* a16      = (unsigned*)p;  p += (size_t)B * N * 64 * 4;
    unsigned* bp16     = (unsigned*)p;  p += (size_t)B * N * 64 * 4;
    int*      src_csr  = (int*)p;       p += (size_t)SE * 4;
    float*    e_spill  = (float*)p;     p += (size_t)B * E * 4;
    int*      cnt      = (int*)p;       p += (size_t)S * N * 4;
    int*      row_off  = (int*)p;       p += (size_t)S * (N + 1) * 4;
    int*      partials = (int*)p;       p += (size_t)S * BPS * 4;
    int*      scanned  = (int*)p;

    const int n4 = N * F / 4;
    const int proj_blocks = (N + 63) / 64;
    const int se_blocks   = (SE + 255) / 256;
    const int node_blocks = (N + 3) / 4;

    cvt_feat_kernel<<<2048, 256, 0, stream>>>(feat, feat16, n4);
    hipMemsetAsync(cnt, 0, (size_t)S * N * sizeof(int), stream);
    count_all_kernel<<<se_blocks, 256, 0, stream>>>(dst, cnt, E, SE, N);
    partial_kernel<<<dim3(BPS, S), 256, 0, stream>>>(cnt, partials, N, BPS);
    scan_partials_kernel<<<1, 1024, 0, stream>>>(partials, scanned, row_off, S, BPS, N);
    emit_kernel<<<dim3(BPS, S), 256, 0, stream>>>(cnt, scanned, row_off, cnt, N, BPS);
    fill_all_kernel<<<se_blocks, 256, 0, stream>>>(src, dst, cnt, src_csr, E, SE, N);

    for (int k0 = 0; k0 < S; k0 += B) {
        proj_kernel<<<dim3(proj_blocks, B), 256, 0, stream>>>(
            feat, W, bvec, a16, bp16, N, k0);
        fused_kernel<<<dim3(node_blocks, B), 256, 0, stream>>>(
            (const uint4*)feat16, (const uint4*)a16, (const uint4*)bp16, wout,
            src_csr, row_off, e_spill, out, N, S, E, k0);
    }
}

// Round 5
// 560.841 us; speedup vs baseline: 3.3930x; 1.4983x over previous
//
#include <hip/hip_runtime.h>
#include <hip/hip_bf16.h>

// AngleOrientedConv: per space k (S=4):
//   a  = feat @ W[k][:128,:];  bp = feat @ W[k][128:,:] + b[k]
//   e  = sum_j tanh(a[src][j] + bp[dst][j]) * w[k][j]
//   segment softmax over dst; out[:, k*128:(k+1)*128] = sum alpha * feat[src]
//
// Round 5: replace the scattered-write CSR build (fill_all was 258us: every
// 4B scatter cost a 64B HBM line writeback) with two-level bucket binning:
// bin by dst>>8 (packed u32 records, LDS-reserve scatter), then per-bucket
// node-count + CSR fill with LDS cursors -> all scatter is L2-window-local.

#define F 128
#define CAP 256   // per-wave LDS e-buffer entries; degree > CAP spills to global

__device__ __forceinline__ unsigned f2bf(float x) {  // round-to-nearest-even
    unsigned u = __float_as_uint(x);
    unsigned r = ((u >> 16) & 1u) + 0x7fffu;
    return (u + r) >> 16;
}
__device__ __forceinline__ float bf_lo(unsigned v) { return __uint_as_float(v << 16); }
__device__ __forceinline__ float bf_hi(unsigned v) { return __uint_as_float(v & 0xffff0000u); }

__device__ __forceinline__ float fast_tanh(float x) {
    float ex = __expf(2.f * x);
    return 1.f - 2.f * __builtin_amdgcn_rcpf(ex + 1.f);
}

// ---------------- feat -> bf16 (once) ----------------
__global__ __launch_bounds__(256) void cvt_feat_kernel(
    const float* __restrict__ feat, unsigned* __restrict__ feat16, int n4)
{
    for (int i = blockIdx.x * 256 + threadIdx.x; i < n4; i += gridDim.x * 256) {
        float4 v = *(const float4*)(feat + (size_t)i * 4);
        unsigned lo = f2bf(v.x) | (f2bf(v.y) << 16);
        unsigned hi = f2bf(v.z) | (f2bf(v.w) << 16);
        *(uint2*)(feat16 + (size_t)i * 2) = make_uint2(lo, hi);
    }
}

// ---------------- proj (batched over spaces via blockIdx.y) ----------------
__global__ __launch_bounds__(256) void proj_kernel(
    const float* __restrict__ feat, const float* __restrict__ W,
    const float* __restrict__ bvec, unsigned* __restrict__ a16,
    unsigned* __restrict__ bp16, int N, int k0)
{
    __shared__ float sf[64 * 128];
    const int t = threadIdx.x;
    const int n0 = blockIdx.x * 64;
    const int by = blockIdx.y;
    const int k = k0 + by;

    #pragma unroll
    for (int p = 0; p < 8; ++p) {
        int idx4 = p * 256 + t;
        int r = idx4 >> 5;
        int ic = (idx4 & 31) * 4;
        int node = n0 + r;
        float4 v = make_float4(0.f, 0.f, 0.f, 0.f);
        if (node < N) v = *(const float4*)(feat + (size_t)node * F + ic);
        *(float4*)(sf + r * F + ic) = v;
    }
    __syncthreads();

    const int mat = t >> 7;
    const int ng  = (t >> 6) & 1;
    const int cp  = t & 63;
    const int c0  = cp * 2;
    const float* Wb = W + (size_t)k * 2 * F * F + (size_t)(mat * F) * F;

    float acc0[32], acc1[32];
    #pragma unroll
    for (int r = 0; r < 32; ++r) { acc0[r] = 0.f; acc1[r] = 0.f; }

    for (int i0 = 0; i0 < F; i0 += 4) {
        float2 wv0 = *(const float2*)(Wb + (size_t)(i0 + 0) * F + c0);
        float2 wv1 = *(const float2*)(Wb + (size_t)(i0 + 1) * F + c0);
        float2 wv2 = *(const float2*)(Wb + (size_t)(i0 + 2) * F + c0);
        float2 wv3 = *(const float2*)(Wb + (size_t)(i0 + 3) * F + c0);
        const float* sp = sf + (ng * 32) * F + i0;
        #pragma unroll
        for (int r = 0; r < 32; ++r) {
            float4 v = *(const float4*)(sp + r * F);
            acc0[r] += v.x * wv0.x + v.y * wv1.x + v.z * wv2.x + v.w * wv3.x;
            acc1[r] += v.x * wv0.y + v.y * wv1.y + v.z * wv2.y + v.w * wv3.y;
        }
    }

    float2 bw = make_float2(0.f, 0.f);
    if (mat == 1) bw = *(const float2*)(bvec + (size_t)k * F + c0);
    unsigned* dstp = (mat ? bp16 : a16) + (size_t)by * N * 64;
    #pragma unroll
    for (int r = 0; r < 32; ++r) {
        int node = n0 + ng * 32 + r;
        if (node < N) {
            unsigned o = f2bf(acc0[r] + bw.x) | (f2bf(acc1[r] + bw.y) << 16);
            dstp[(size_t)node * 64 + cp] = o;
        }
    }
}

// ============= bucket-binned CSR build (N <= 65536 path) =============
// bucket id = s*NB + (dst>>8); record = src | ((dst&255) << 16)

__global__ __launch_bounds__(256) void bucket_count_kernel(
    const int* __restrict__ dst, int* __restrict__ bkt_cnt,
    int E, int SE, int NB, int NBS)
{
    __shared__ int hist[1024];
    const int t = threadIdx.x;
    for (int i = t; i < NBS; i += 256) hist[i] = 0;
    __syncthreads();
    const int chunk = (SE + gridDim.x - 1) / gridDim.x;
    const int e0 = blockIdx.x * chunk;
    const int e1 = min(SE, e0 + chunk);
    for (int e = e0 + t; e < e1; e += 256) {
        int s = e / E;
        atomicAdd(&hist[s * NB + (dst[e] >> 8)], 1);
    }
    __syncthreads();
    for (int i = t; i < NBS; i += 256)
        if (hist[i]) atomicAdd(&bkt_cnt[i], hist[i]);
}

__global__ __launch_bounds__(1024) void bucket_scan_kernel(
    const int* __restrict__ bkt_cnt, int* __restrict__ bkt_off,
    int* __restrict__ bkt_cur, int NBS)
{
    __shared__ int buf[1024];
    const int t = threadIdx.x;
    buf[t] = (t < NBS) ? bkt_cnt[t] : 0;
    __syncthreads();
    for (int off = 1; off < 1024; off <<= 1) {
        int x = (t >= off) ? buf[t - off] : 0;
        __syncthreads();
        buf[t] += x;
        __syncthreads();
    }
    if (t <= NBS) {
        int v = (t == 0) ? 0 : buf[t - 1];
        bkt_off[t] = v;
        if (t < NBS) bkt_cur[t] = v;
    }
}

__global__ __launch_bounds__(256) void bucket_scatter_kernel(
    const int* __restrict__ src, const int* __restrict__ dst,
    int* __restrict__ bkt_cur, unsigned* __restrict__ recs,
    int E, int SE, int NB, int NBS)
{
    __shared__ int hist[1024];
    __shared__ int base[1024];
    const int t = threadIdx.x;
    for (int i = t; i < NBS; i += 256) hist[i] = 0;
    __syncthreads();
    const int chunk = (SE + gridDim.x - 1) / gridDim.x;
    const int e0 = blockIdx.x * chunk;
    const int e1 = min(SE, e0 + chunk);
    for (int e = e0 + t; e < e1; e += 256) {
        int s = e / E;
        atomicAdd(&hist[s * NB + (dst[e] >> 8)], 1);
    }
    __syncthreads();
    for (int i = t; i < NBS; i += 256) {
        int h = hist[i];
        if (h) base[i] = atomicAdd(&bkt_cur[i], h);
        hist[i] = 0;
    }
    __syncthreads();
    for (int e = e0 + t; e < e1; e += 256) {
        int s = e / E;
        int d = dst[e];
        int gb = s * NB + (d >> 8);
        int lo = atomicAdd(&hist[gb], 1);
        recs[base[gb] + lo] = (unsigned)src[e] | ((unsigned)(d & 255) << 16);
    }
}

// per-bucket node counts (no global atomics, coalesced writes)
__global__ __launch_bounds__(256) void node_count_bucket_kernel(
    const unsigned* __restrict__ recs, const int* __restrict__ bkt_off,
    int* __restrict__ cnt, int N, int NB)
{
    __shared__ int hist[256];
    const int t = threadIdx.x;
    const int gb = blockIdx.x;
    const int s = gb / NB;
    const int node0 = (gb % NB) << 8;
    hist[t] = 0;
    __syncthreads();
    const int r0 = bkt_off[gb], r1 = bkt_off[gb + 1];
    for (int r = r0 + t; r < r1; r += 256)
        atomicAdd(&hist[(recs[r] >> 16) & 255], 1);
    __syncthreads();
    int node = node0 + t;
    if (node < N) cnt[(size_t)s * N + node] = hist[t];
}

// hierarchical scan over cnt -> row_off
__global__ __launch_bounds__(256) void partial_kernel(
    const int* __restrict__ cnt, int* __restrict__ partials, int N, int BPS)
{
    __shared__ int red[256];
    const int s = blockIdx.y, b = blockIdx.x, t = threadIdx.x;
    int i = b * 256 + t;
    red[t] = (i < N) ? cnt[(size_t)s * N + i] : 0;
    __syncthreads();
    #pragma unroll
    for (int off = 128; off; off >>= 1) {
        if (t < off) red[t] += red[t + off];
        __syncthreads();
    }
    if (t == 0) partials[s * BPS + b] = red[0];
}

__global__ __launch_bounds__(1024) void scan_partials_kernel(
    const int* __restrict__ partials, int* __restrict__ scanned,
    int* __restrict__ row_off, int S, int BPS, int N)
{
    __shared__ int buf[1024];
    const int t = threadIdx.x;
    const int total = S * BPS;
    buf[t] = (t < total) ? partials[t] : 0;
    __syncthreads();
    for (int off = 1; off < 1024; off <<= 1) {
        int x = (t >= off) ? buf[t - off] : 0;
        __syncthreads();
        buf[t] += x;
        __syncthreads();
    }
    if (t < total) {
        int s = t / BPS;
        int g_excl = (t == 0) ? 0 : buf[t - 1];
        int base = (s == 0) ? 0 : buf[s * BPS - 1];
        scanned[t] = g_excl - base;
    }
    if (t < S) {
        int end  = buf[(t + 1) * BPS - 1];
        int base = (t == 0) ? 0 : buf[t * BPS - 1];
        row_off[(size_t)t * (N + 1) + N] = end - base;
    }
}

__global__ __launch_bounds__(256) void emit_kernel(
    const int* __restrict__ cnt, const int* __restrict__ scanned,
    int* __restrict__ row_off, int N, int BPS)
{
    __shared__ int buf[256];
    const int s = blockIdx.y, b = blockIdx.x, t = threadIdx.x;
    int i = b * 256 + t;
    int v = (i < N) ? cnt[(size_t)s * N + i] : 0;
    buf[t] = v;
    __syncthreads();
    for (int off = 1; off < 256; off <<= 1) {
        int x = (t >= off) ? buf[t - off] : 0;
        __syncthreads();
        buf[t] += x;
        __syncthreads();
    }
    if (i < N)
        row_off[(size_t)s * (N + 1) + i] = scanned[s * BPS + b] + buf[t] - v;
}

// per-bucket CSR fill: LDS cursors, scatter stays in bucket's L2 window
__global__ __launch_bounds__(256) void csr_fill_bucket_kernel(
    const unsigned* __restrict__ recs, const int* __restrict__ bkt_off,
    const int* __restrict__ row_off, int* __restrict__ src_csr,
    int N, int E, int NB)
{
    __shared__ int cur[256];
    const int t = threadIdx.x;
    const int gb = blockIdx.x;
    const int s = gb / NB;
    const int node0 = (gb % NB) << 8;
    int node = node0 + t;
    cur[t] = (node < N) ? row_off[(size_t)s * (N + 1) + node] : 0;
    __syncthreads();
    int* csr = src_csr + (size_t)s * E;
    const int r0 = bkt_off[gb], r1 = bkt_off[gb + 1];
    for (int r = r0 + t; r < r1; r += 256) {
        unsigned rec = recs[r];
        int pos = atomicAdd(&cur[(rec >> 16) & 255], 1);
        csr[pos] = (int)(rec & 0xFFFFu);
    }
}

// ============= fallback CSR build (N > 65536) =============
__global__ __launch_bounds__(256) void count_all_kernel(
    const int* __restrict__ dst, int* __restrict__ cnt, int E, int SE, int N)
{
    int e = blockIdx.x * 256 + threadIdx.x;
    if (e < SE) {
        int s = e / E;
        atomicAdd(&cnt[(size_t)s * N + dst[e]], 1);
    }
}
__global__ __launch_bounds__(256) void emit_cursor_kernel(
    const int* __restrict__ row_off, int* __restrict__ cursor, int N)
{
    const int s = blockIdx.y;
    int i = blockIdx.x * 256 + threadIdx.x;
    if (i < N) cursor[(size_t)s * N + i] = row_off[(size_t)s * (N + 1) + i];
}
__global__ __launch_bounds__(256) void fill_all_kernel(
    const int* __restrict__ src, const int* __restrict__ dst,
    int* __restrict__ cursor, int* __restrict__ src_csr,
    int E, int SE, int N)
{
    int e = blockIdx.x * 256 + threadIdx.x;
    if (e < SE) {
        int s = e / E;
        int pos = atomicAdd(&cursor[(size_t)s * N + dst[e]], 1);
        src_csr[(size_t)s * E + pos] = src[e];
    }
}

// ---------------- fused attention+softmax+gather: 16 lanes/edge ----------
__global__ __launch_bounds__(256) void fused_kernel(
    const uint4* __restrict__ feat16, const uint4* __restrict__ a16,
    const uint4* __restrict__ bp16, const float* __restrict__ wout,
    const int* __restrict__ src_csr_all, const int* __restrict__ row_off_all,
    float* __restrict__ e_spill, float* __restrict__ out,
    int N, int S, int E, int k0)
{
    __shared__ float els[4][CAP];
    const int by = blockIdx.y;
    const int k = k0 + by;
    const int wslot = threadIdx.x >> 6;
    const int node = blockIdx.x * 4 + wslot;
    const int lane = threadIdx.x & 63;
    const int eg = lane >> 4;
    const int fl = lane & 15;
    if (node >= N) return;

    const int* row_off = row_off_all + (size_t)k * (N + 1);
    const int* src_csr = src_csr_all + (size_t)k * E;
    float* spill = e_spill + (size_t)by * E;
    const uint4* a16k  = a16  + (size_t)by * N * 16;
    const uint4* bp16k = bp16 + (size_t)by * N * 16;

    const int beg = row_off[node];
    const int cnt = row_off[node + 1] - beg;
    float* outp = out + (size_t)node * (S * F) + k * F;
    if (cnt == 0) {
        if (eg == 0) {
            *(float4*)(outp + fl * 8)     = make_float4(0.f, 0.f, 0.f, 0.f);
            *(float4*)(outp + fl * 8 + 4) = make_float4(0.f, 0.f, 0.f, 0.f);
        }
        return;
    }

    uint4 bv = bp16k[(size_t)node * 16 + fl];
    const float b0 = bf_lo(bv.x), b1 = bf_hi(bv.x);
    const float b2 = bf_lo(bv.y), b3 = bf_hi(bv.y);
    const float b4 = bf_lo(bv.z), b5 = bf_hi(bv.z);
    const float b6 = bf_lo(bv.w), b7 = bf_hi(bv.w);
    const float4* w4 = (const float4*)(wout + (size_t)k * F);
    const float4 w0 = w4[fl * 2];
    const float4 w1 = w4[fl * 2 + 1];

    float m = -INFINITY;
    for (int chunk = 0; chunk < cnt; chunk += 64) {
        int idx = chunk + lane;
        int sv = (idx < cnt) ? src_csr[beg + idx] : 0;
        int cend = min(64, cnt - chunk);
        for (int q = 0; q < cend; q += 4) {
            int my = q + eg;
            int sj = __shfl(sv, my);
            uint4 av = a16k[(size_t)sj * 16 + fl];
            float p = fast_tanh(bf_lo(av.x) + b0) * w0.x
                    + fast_tanh(bf_hi(av.x) + b1) * w0.y
                    + fast_tanh(bf_lo(av.y) + b2) * w0.z
                    + fast_tanh(bf_hi(av.y) + b3) * w0.w
                    + fast_tanh(bf_lo(av.z) + b4) * w1.x
                    + fast_tanh(bf_hi(av.z) + b5) * w1.y
                    + fast_tanh(bf_lo(av.w) + b6) * w1.z
                    + fast_tanh(bf_hi(av.w) + b7) * w1.w;
            p += __shfl_xor(p, 1); p += __shfl_xor(p, 2);
            p += __shfl_xor(p, 4); p += __shfl_xor(p, 8);
            if (my < cend) {
                m = fmaxf(m, p);
                if (fl == 0) {
                    int pos = chunk + my;
                    if (pos < CAP) els[wslot][pos] = p;
                    else           spill[beg + pos] = p;
                }
            }
        }
    }
    m = fmaxf(m, __shfl_xor(m, 16));
    m = fmaxf(m, __shfl_xor(m, 32));

    float ssum = 0.f;
    float acc[8] = {0.f, 0.f, 0.f, 0.f, 0.f, 0.f, 0.f, 0.f};
    for (int chunk = 0; chunk < cnt; chunk += 64) {
        int idx = chunk + lane;
        int sv = 0;
        float exl = 0.f;
        if (idx < cnt) {
            sv = src_csr[beg + idx];
            float ev = (idx < CAP) ? els[wslot][idx] : spill[beg + idx];
            exl = __expf(ev - m);
        }
        ssum += exl;
        int cend = min(64, cnt - chunk);
        for (int q = 0; q < cend; q += 4) {
            int my = q + eg;
            int sj = __shfl(sv, my);
            float exj = __shfl(exl, my);
            uint4 fv = feat16[(size_t)sj * 16 + fl];
            acc[0] += exj * bf_lo(fv.x); acc[1] += exj * bf_hi(fv.x);
            acc[2] += exj * bf_lo(fv.y); acc[3] += exj * bf_hi(fv.y);
            acc[4] += exj * bf_lo(fv.z); acc[5] += exj * bf_hi(fv.z);
            acc[6] += exj * bf_lo(fv.w); acc[7] += exj * bf_hi(fv.w);
        }
    }
    #pragma unroll
    for (int off = 32; off; off >>= 1) ssum += __shfl_xor(ssum, off);
    #pragma unroll
    for (int j = 0; j < 8; ++j) {
        acc[j] += __shfl_xor(acc[j], 16);
        acc[j] += __shfl_xor(acc[j], 32);
    }
    float inv = __builtin_amdgcn_rcpf(ssum);
    if (eg == 0) {
        *(float4*)(outp + fl * 8) =
            make_float4(acc[0] * inv, acc[1] * inv, acc[2] * inv, acc[3] * inv);
        *(float4*)(outp + fl * 8 + 4) =
            make_float4(acc[4] * inv, acc[5] * inv, acc[6] * inv, acc[7] * inv);
    }
}

extern "C" void kernel_launch(void* const* d_in, const int* in_sizes, int n_in,
                              void* d_out, int out_size, void* d_ws, size_t ws_size,
                              hipStream_t stream) {
    const float* feat = (const float*)d_in[0];
    const int*   src  = (const int*)d_in[1];
    const int*   dst  = (const int*)d_in[2];
    const float* W    = (const float*)d_in[3];
    const float* bvec = (const float*)d_in[4];
    const float* wout = (const float*)d_in[5];
    float* out = (float*)d_out;

    const int N = in_sizes[0] / F;
    const int S = in_sizes[3] / (2 * F * F);
    const int E = in_sizes[1] / S;
    const int SE = S * E;
    const int BPS = (N + 255) / 256;
    const int NB  = (N + 255) >> 8;
    const int NBS = NB * S;
    const bool packed = (N <= 65536) && (NBS <= 1024) && (S * BPS <= 1024);

    size_t fixed = (size_t)N * 64 * 4            // feat16
                 + (size_t)SE * 4                // src_csr
                 + (size_t)S * N * 4             // cnt
                 + (size_t)S * (N + 1) * 4       // row_off
                 + (size_t)S * BPS * 4 * 2       // partials + scanned
                 + (size_t)(NBS + 1) * 4 * 3;    // bkt_cnt + bkt_off + bkt_cur
    size_t perB = (size_t)N * 64 * 4 * 2;        // a16 + bp16
    size_t spill_union_S = (size_t)(SE > S * 0 ? SE : SE) * 4;  // max(S*E, SE)*4
    size_t need_S = fixed + perB * S + spill_union_S + 1024;
    const int B = (ws_size >= need_S) ? S : 1;

    char* p = (char*)d_ws;
    unsigned* feat16   = (unsigned*)p;  p += (size_t)N * 64 * 4;
    unsigned* a16      = (unsigned*)p;  p += (size_t)B * N * 64 * 4;
    unsigned* bp16     = (unsigned*)p;  p += (size_t)B * N * 64 * 4;
    int*      src_csr  = (int*)p;       p += (size_t)SE * 4;
    // union: recs (SE u32, CSR build) / e_spill (B*E floats, fused)
    size_t union_bytes = ((size_t)SE * 4 > (size_t)B * E * 4) ? (size_t)SE * 4
                                                              : (size_t)B * E * 4;
    unsigned* recs     = (unsigned*)p;
    float*    e_spill  = (float*)p;     p += union_bytes;
    int*      cnt      = (int*)p;       p += (size_t)S * N * 4;
    int*      row_off  = (int*)p;       p += (size_t)S * (N + 1) * 4;
    int*      partials = (int*)p;       p += (size_t)S * BPS * 4;
    int*      scanned  = (int*)p;       p += (size_t)S * BPS * 4;
    int*      bkt_cnt  = (int*)p;       p += (size_t)(NBS + 1) * 4;
    int*      bkt_off  = (int*)p;       p += (size_t)(NBS + 1) * 4;
    int*      bkt_cur  = (int*)p;

    const int n4 = N * F / 4;
    const int proj_blocks = (N + 63) / 64;
    const int node_blocks = (N + 3) / 4;
    const int se_blocks   = (SE + 255) / 256;

    cvt_feat_kernel<<<2048, 256, 0, stream>>>(feat, feat16, n4);

    if (packed) {
        hipMemsetAsync(bkt_cnt, 0, (size_t)NBS * sizeof(int), stream);
        bucket_count_kernel<<<256, 256, 0, stream>>>(dst, bkt_cnt, E, SE, NB, NBS);
        bucket_scan_kernel<<<1, 1024, 0, stream>>>(bkt_cnt, bkt_off, bkt_cur, NBS);
        bucket_scatter_kernel<<<256, 256, 0, stream>>>(src, dst, bkt_cur, recs,
                                                       E, SE, NB, NBS);
        node_count_bucket_kernel<<<NBS, 256, 0, stream>>>(recs, bkt_off, cnt, N, NB);
        partial_kernel<<<dim3(BPS, S), 256, 0, stream>>>(cnt, partials, N, BPS);
        scan_partials_kernel<<<1, 1024, 0, stream>>>(partials, scanned, row_off,
                                                     S, BPS, N);
        emit_kernel<<<dim3(BPS, S), 256, 0, stream>>>(cnt, scanned, row_off, N, BPS);
        csr_fill_bucket_kernel<<<NBS, 256, 0, stream>>>(recs, bkt_off, row_off,
                                                        src_csr, N, E, NB);
    } else {
        hipMemsetAsync(cnt, 0, (size_t)S * N * sizeof(int), stream);
        count_all_kernel<<<se_blocks, 256, 0, stream>>>(dst, cnt, E, SE, N);
        partial_kernel<<<dim3(BPS, S), 256, 0, stream>>>(cnt, partials, N, BPS);
        scan_partials_kernel<<<1, 1024, 0, stream>>>(partials, scanned, row_off,
                                                     S, BPS, N);
        emit_kernel<<<dim3(BPS, S), 256, 0, stream>>>(cnt, scanned, row_off, N, BPS);
        emit_cursor_kernel<<<dim3(BPS, S), 256, 0, stream>>>(row_off, cnt, N);
        fill_all_kernel<<<se_blocks, 256, 0, stream>>>(src, dst, cnt, src_csr,
                                                       E, SE, N);
    }

    for (int k0 = 0; k0 < S; k0 += B) {
        proj_kernel<<<dim3(proj_blocks, B), 256, 0, stream>>>(
            feat, W, bvec, a16, bp16, N, k0);
        fused_kernel<<<dim3(node_blocks, B), 256, 0, stream>>>(
            (const uint4*)feat16, (const uint4*)a16, (const uint4*)bp16, wout,
            src_csr, row_off, e_spill, out, N, S, E, k0);
    }
}

// Round 6
// 485.595 us; speedup vs baseline: 3.9188x; 1.1550x over previous
//
#include <hip/hip_runtime.h>
#include <hip/hip_bf16.h>

// AngleOrientedConv: per space k (S=4):
//   a  = feat @ W[k][:128,:];  bp = feat @ W[k][128:,:] + b[k]
//   e  = sum_j tanh(a[src][j] + bp[dst][j]) * w[k][j]
//   segment softmax over dst; out[:, k*128:(k+1)*128] = sum alpha * feat[src]
//
// Round 6:
//  * fused kernel: SINGLE PASS. |e| <= sum|w| (hard bound), so softmax uses the
//    per-space shift sum|w| instead of the per-node max -> identical alpha, no
//    max pass, no e storage, no LDS. tanh folded to fma+exp2+add+rcp+fma.
//  * proj via bf16 MFMA (16x16x32): [a||bp] = feat16 @ Wc, W pre-transposed
//    to bf16 once. ~13 GFLOP on matrix pipe instead of fp32 VALU.

#define F 128

typedef __attribute__((ext_vector_type(8))) short short8v;   // 8 bf16
typedef __attribute__((ext_vector_type(4))) float f32x4;

__device__ __forceinline__ unsigned f2bf(float x) {  // round-to-nearest-even
    unsigned u = __float_as_uint(x);
    unsigned r = ((u >> 16) & 1u) + 0x7fffu;
    return (u + r) >> 16;
}
__device__ __forceinline__ float bf_lo(unsigned v) { return __uint_as_float(v << 16); }
__device__ __forceinline__ float bf_hi(unsigned v) { return __uint_as_float(v & 0xffff0000u); }

// ---------------- feat -> bf16 (once) ----------------
__global__ __launch_bounds__(256) void cvt_feat_kernel(
    const float* __restrict__ feat, unsigned* __restrict__ feat16, int n4)
{
    for (int i = blockIdx.x * 256 + threadIdx.x; i < n4; i += gridDim.x * 256) {
        float4 v = *(const float4*)(feat + (size_t)i * 4);
        unsigned lo = f2bf(v.x) | (f2bf(v.y) << 16);
        unsigned hi = f2bf(v.z) | (f2bf(v.w) << 16);
        *(uint2*)(feat16 + (size_t)i * 2) = make_uint2(lo, hi);
    }
}

// ---------------- W -> transposed bf16: Wt[s][c(256)][k(128)] ----------------
// Wt[s][c][i] = W[s][(c>=128?128:0)+i][c&127]
__global__ __launch_bounds__(256) void cvt_w_kernel(
    const float* __restrict__ W, unsigned short* __restrict__ Wt, int total)
{
    int tid = blockIdx.x * 256 + threadIdx.x;
    if (tid >= total) return;
    int i = tid & 127;
    int c = (tid >> 7) & 255;
    int s = tid >> 15;
    float v = W[(size_t)s * 32768 + (size_t)(((c >> 7) << 7) + i) * 128 + (c & 127)];
    Wt[tid] = (unsigned short)f2bf(v);
}

// ---------------- proj via MFMA: [a||bp](bf16) = feat16 @ Wt^T + bias -------
// block = 4 waves, 64 rows; wave w: rows row0..row0+15, all 256 cols.
__global__ __launch_bounds__(256) void proj_mfma_kernel(
    const unsigned short* __restrict__ feat16s,
    const unsigned short* __restrict__ WtAll,
    const float* __restrict__ bvec,
    unsigned short* __restrict__ a16s, unsigned short* __restrict__ bp16s,
    int N, int k0)
{
    const int t = threadIdx.x;
    const int w = t >> 6, l = t & 63;
    const int by = blockIdx.y, k = k0 + by;
    const int row0 = blockIdx.x * 64 + w * 16;
    const unsigned short* Wk = WtAll + (size_t)k * 256 * 128;

    const int lrow = l & 15;
    const int lk = (l >> 4) * 8;

    f32x4 acc[16];
    #pragma unroll
    for (int jt = 0; jt < 16; ++jt) acc[jt] = (f32x4){0.f, 0.f, 0.f, 0.f};

    const int arow = row0 + lrow;
    const bool aok = arow < N;
    const unsigned short* ap = feat16s + (size_t)arow * 128 + lk;

    #pragma unroll
    for (int kk = 0; kk < 4; ++kk) {
        short8v af = {0, 0, 0, 0, 0, 0, 0, 0};
        if (aok) af = *(const short8v*)(ap + kk * 32);
        #pragma unroll
        for (int jt = 0; jt < 16; ++jt) {
            short8v bf = *(const short8v*)(Wk + (size_t)(jt * 16 + lrow) * 128 + kk * 32 + lk);
            acc[jt] = __builtin_amdgcn_mfma_f32_16x16x32_bf16(af, bf, acc[jt], 0, 0, 0);
        }
    }

    // epilogue: C/D layout col=lane&15, row=(lane>>4)*4+reg (m89-verified)
    unsigned short* a16k  = a16s  + (size_t)by * N * 128;
    unsigned short* bp16k = bp16s + (size_t)by * N * 128;
    #pragma unroll
    for (int jt = 0; jt < 16; ++jt) {
        const int col = jt * 16 + lrow;          // 0..255 (uniform half per jt)
        const int c = col & 127;
        const bool isb = (jt >= 8);
        float bias = isb ? bvec[(size_t)k * F + c] : 0.f;
        unsigned short* dstp = isb ? bp16k : a16k;
        #pragma unroll
        for (int r = 0; r < 4; ++r) {
            int node = row0 + (l >> 4) * 4 + r;
            if (node < N)
                dstp[(size_t)node * 128 + c] = (unsigned short)f2bf(acc[jt][r] + bias);
        }
    }
}

// ============= bucket-binned CSR build (N <= 65536 path) =============
__global__ __launch_bounds__(256) void bucket_count_kernel(
    const int* __restrict__ dst, int* __restrict__ bkt_cnt,
    int E, int SE, int NB, int NBS)
{
    __shared__ int hist[1024];
    const int t = threadIdx.x;
    for (int i = t; i < NBS; i += 256) hist[i] = 0;
    __syncthreads();
    const int chunk = (SE + gridDim.x - 1) / gridDim.x;
    const int e0 = blockIdx.x * chunk;
    const int e1 = min(SE, e0 + chunk);
    for (int e = e0 + t; e < e1; e += 256) {
        int s = e / E;
        atomicAdd(&hist[s * NB + (dst[e] >> 8)], 1);
    }
    __syncthreads();
    for (int i = t; i < NBS; i += 256)
        if (hist[i]) atomicAdd(&bkt_cnt[i], hist[i]);
}

__global__ __launch_bounds__(1024) void bucket_scan_kernel(
    const int* __restrict__ bkt_cnt, int* __restrict__ bkt_off,
    int* __restrict__ bkt_cur, int NBS)
{
    __shared__ int buf[1024];
    const int t = threadIdx.x;
    buf[t] = (t < NBS) ? bkt_cnt[t] : 0;
    __syncthreads();
    for (int off = 1; off < 1024; off <<= 1) {
        int x = (t >= off) ? buf[t - off] : 0;
        __syncthreads();
        buf[t] += x;
        __syncthreads();
    }
    if (t <= NBS) {
        int v = (t == 0) ? 0 : buf[t - 1];
        bkt_off[t] = v;
        if (t < NBS) bkt_cur[t] = v;
    }
}

__global__ __launch_bounds__(256) void bucket_scatter_kernel(
    const int* __restrict__ src, const int* __restrict__ dst,
    int* __restrict__ bkt_cur, unsigned* __restrict__ recs,
    int E, int SE, int NB, int NBS)
{
    __shared__ int hist[1024];
    __shared__ int base[1024];
    const int t = threadIdx.x;
    for (int i = t; i < NBS; i += 256) hist[i] = 0;
    __syncthreads();
    const int chunk = (SE + gridDim.x - 1) / gridDim.x;
    const int e0 = blockIdx.x * chunk;
    const int e1 = min(SE, e0 + chunk);
    for (int e = e0 + t; e < e1; e += 256) {
        int s = e / E;
        atomicAdd(&hist[s * NB + (dst[e] >> 8)], 1);
    }
    __syncthreads();
    for (int i = t; i < NBS; i += 256) {
        int h = hist[i];
        if (h) base[i] = atomicAdd(&bkt_cur[i], h);
        hist[i] = 0;
    }
    __syncthreads();
    for (int e = e0 + t; e < e1; e += 256) {
        int s = e / E;
        int d = dst[e];
        int gb = s * NB + (d >> 8);
        int lo = atomicAdd(&hist[gb], 1);
        recs[base[gb] + lo] = (unsigned)src[e] | ((unsigned)(d & 255) << 16);
    }
}

__global__ __launch_bounds__(256) void node_count_bucket_kernel(
    const unsigned* __restrict__ recs, const int* __restrict__ bkt_off,
    int* __restrict__ cnt, int N, int NB)
{
    __shared__ int hist[256];
    const int t = threadIdx.x;
    const int gb = blockIdx.x;
    const int s = gb / NB;
    const int node0 = (gb % NB) << 8;
    hist[t] = 0;
    __syncthreads();
    const int r0 = bkt_off[gb], r1 = bkt_off[gb + 1];
    for (int r = r0 + t; r < r1; r += 256)
        atomicAdd(&hist[(recs[r] >> 16) & 255], 1);
    __syncthreads();
    int node = node0 + t;
    if (node < N) cnt[(size_t)s * N + node] = hist[t];
}

__global__ __launch_bounds__(256) void partial_kernel(
    const int* __restrict__ cnt, int* __restrict__ partials, int N, int BPS)
{
    __shared__ int red[256];
    const int s = blockIdx.y, b = blockIdx.x, t = threadIdx.x;
    int i = b * 256 + t;
    red[t] = (i < N) ? cnt[(size_t)s * N + i] : 0;
    __syncthreads();
    #pragma unroll
    for (int off = 128; off; off >>= 1) {
        if (t < off) red[t] += red[t + off];
        __syncthreads();
    }
    if (t == 0) partials[s * BPS + b] = red[0];
}

__global__ __launch_bounds__(1024) void scan_partials_kernel(
    const int* __restrict__ partials, int* __restrict__ scanned,
    int* __restrict__ row_off, int S, int BPS, int N)
{
    __shared__ int buf[1024];
    const int t = threadIdx.x;
    const int total = S * BPS;
    buf[t] = (t < total) ? partials[t] : 0;
    __syncthreads();
    for (int off = 1; off < 1024; off <<= 1) {
        int x = (t >= off) ? buf[t - off] : 0;
        __syncthreads();
        buf[t] += x;
        __syncthreads();
    }
    if (t < total) {
        int s = t / BPS;
        int g_excl = (t == 0) ? 0 : buf[t - 1];
        int base = (s == 0) ? 0 : buf[s * BPS - 1];
        scanned[t] = g_excl - base;
    }
    if (t < S) {
        int end  = buf[(t + 1) * BPS - 1];
        int base = (t == 0) ? 0 : buf[t * BPS - 1];
        row_off[(size_t)t * (N + 1) + N] = end - base;
    }
}

__global__ __launch_bounds__(256) void emit_kernel(
    const int* __restrict__ cnt, const int* __restrict__ scanned,
    int* __restrict__ row_off, int N, int BPS)
{
    __shared__ int buf[256];
    const int s = blockIdx.y, b = blockIdx.x, t = threadIdx.x;
    int i = b * 256 + t;
    int v = (i < N) ? cnt[(size_t)s * N + i] : 0;
    buf[t] = v;
    __syncthreads();
    for (int off = 1; off < 256; off <<= 1) {
        int x = (t >= off) ? buf[t - off] : 0;
        __syncthreads();
        buf[t] += x;
        __syncthreads();
    }
    if (i < N)
        row_off[(size_t)s * (N + 1) + i] = scanned[s * BPS + b] + buf[t] - v;
}

__global__ __launch_bounds__(256) void csr_fill_bucket_kernel(
    const unsigned* __restrict__ recs, const int* __restrict__ bkt_off,
    const int* __restrict__ row_off, int* __restrict__ src_csr,
    int N, int E, int NB)
{
    __shared__ int cur[256];
    const int t = threadIdx.x;
    const int gb = blockIdx.x;
    const int s = gb / NB;
    const int node0 = (gb % NB) << 8;
    int node = node0 + t;
    cur[t] = (node < N) ? row_off[(size_t)s * (N + 1) + node] : 0;
    __syncthreads();
    int* csr = src_csr + (size_t)s * E;
    const int r0 = bkt_off[gb], r1 = bkt_off[gb + 1];
    for (int r = r0 + t; r < r1; r += 256) {
        unsigned rec = recs[r];
        int pos = atomicAdd(&cur[(rec >> 16) & 255], 1);
        csr[pos] = (int)(rec & 0xFFFFu);
    }
}

// ============= fallback CSR build (N > 65536) =============
__global__ __launch_bounds__(256) void count_all_kernel(
    const int* __restrict__ dst, int* __restrict__ cnt, int E, int SE, int N)
{
    int e = blockIdx.x * 256 + threadIdx.x;
    if (e < SE) {
        int s = e / E;
        atomicAdd(&cnt[(size_t)s * N + dst[e]], 1);
    }
}
__global__ __launch_bounds__(256) void emit_cursor_kernel(
    const int* __restrict__ row_off, int* __restrict__ cursor, int N)
{
    const int s = blockIdx.y;
    int i = blockIdx.x * 256 + threadIdx.x;
    if (i < N) cursor[(size_t)s * N + i] = row_off[(size_t)s * (N + 1) + i];
}
__global__ __launch_bounds__(256) void fill_all_kernel(
    const int* __restrict__ src, const int* __restrict__ dst,
    int* __restrict__ cursor, int* __restrict__ src_csr,
    int E, int SE, int N)
{
    int e = blockIdx.x * 256 + threadIdx.x;
    if (e < SE) {
        int s = e / E;
        int pos = atomicAdd(&cursor[(size_t)s * N + dst[e]], 1);
        src_csr[(size_t)s * E + pos] = src[e];
    }
}

// ------------- fused single-pass attention+softmax+gather -------------
// wave per dst node; 16 lanes per edge, 4 edges in flight; NO max pass:
// alpha = exp(e - sum|w|)/Z  (softmax shift-invariant; |e| <= sum|w| bounds exp)
__global__ __launch_bounds__(256) void fused_kernel(
    const uint4* __restrict__ feat16, const uint4* __restrict__ a16,
    const uint4* __restrict__ bp16, const float* __restrict__ wout,
    const int* __restrict__ src_csr_all, const int* __restrict__ row_off_all,
    float* __restrict__ out, int N, int S, int E, int k0)
{
    const int by = blockIdx.y, k = k0 + by;
    const int wslot = threadIdx.x >> 6;
    const int node = blockIdx.x * 4 + wslot;
    const int lane = threadIdx.x & 63;
    const int eg = lane >> 4;
    const int fl = lane & 15;
    if (node >= N) return;

    const int* row_off = row_off_all + (size_t)k * (N + 1);
    const int* src_csr = src_csr_all + (size_t)k * E;
    const uint4* a16k  = a16  + (size_t)by * N * 16;
    const uint4* bp16k = bp16 + (size_t)by * N * 16;

    const int beg = row_off[node];
    const int cnt = row_off[node + 1] - beg;
    float* outp = out + (size_t)node * (S * F) + k * F;
    if (cnt == 0) {
        if (eg == 0) {
            *(float4*)(outp + fl * 8)     = make_float4(0.f, 0.f, 0.f, 0.f);
            *(float4*)(outp + fl * 8 + 4) = make_float4(0.f, 0.f, 0.f, 0.f);
        }
        return;
    }

    const float C2  = 2.8853900817779268f;   // 2*log2(e)
    const float L2E = 1.4426950408889634f;

    uint4 bv = bp16k[(size_t)node * 16 + fl];
    const float bc0 = bf_lo(bv.x) * C2, bc1 = bf_hi(bv.x) * C2;
    const float bc2 = bf_lo(bv.y) * C2, bc3 = bf_hi(bv.y) * C2;
    const float bc4 = bf_lo(bv.z) * C2, bc5 = bf_hi(bv.z) * C2;
    const float bc6 = bf_lo(bv.w) * C2, bc7 = bf_hi(bv.w) * C2;
    const float4* w4 = (const float4*)(wout + (size_t)k * F);
    const float4 w0 = w4[fl * 2];
    const float4 w1 = w4[fl * 2 + 1];

    float sumw = w0.x + w0.y + w0.z + w0.w + w1.x + w1.y + w1.z + w1.w;
    float sabs = fabsf(w0.x) + fabsf(w0.y) + fabsf(w0.z) + fabsf(w0.w)
               + fabsf(w1.x) + fabsf(w1.y) + fabsf(w1.z) + fabsf(w1.w);
    #pragma unroll
    for (int off = 1; off < 16; off <<= 1) {
        sumw += __shfl_xor(sumw, off);
        sabs += __shfl_xor(sabs, off);
    }
    const float negswl = -sabs * L2E;   // softmax shift (in log2 domain)

    float ssum = 0.f;
    float acc[8] = {0.f, 0.f, 0.f, 0.f, 0.f, 0.f, 0.f, 0.f};
    for (int chunk = 0; chunk < cnt; chunk += 64) {
        int idx = chunk + lane;
        int sv = (idx < cnt) ? src_csr[beg + idx] : 0;
        int cend = min(64, cnt - chunk);
        for (int q = 0; q < cend; q += 4) {
            int my = q + eg;
            int sj = __shfl(sv, my);
            size_t base = (size_t)sj * 16 + fl;
            uint4 av = a16k[base];
            uint4 fv = feat16[base];
            // sum_j w_j * tanh(a_j+b_j) = sumw - 2 * sum_j w_j / (2^(C2*(a+b)) + 1)
            float pr;
            pr  = w0.x * __builtin_amdgcn_rcpf(__builtin_exp2f(fmaf(bf_lo(av.x), C2, bc0)) + 1.f);
            pr += w0.y * __builtin_amdgcn_rcpf(__builtin_exp2f(fmaf(bf_hi(av.x), C2, bc1)) + 1.f);
            pr += w0.z * __builtin_amdgcn_rcpf(__builtin_exp2f(fmaf(bf_lo(av.y), C2, bc2)) + 1.f);
            pr += w0.w * __builtin_amdgcn_rcpf(__builtin_exp2f(fmaf(bf_hi(av.y), C2, bc3)) + 1.f);
            pr += w1.x * __builtin_amdgcn_rcpf(__builtin_exp2f(fmaf(bf_lo(av.z), C2, bc4)) + 1.f);
            pr += w1.y * __builtin_amdgcn_rcpf(__builtin_exp2f(fmaf(bf_hi(av.z), C2, bc5)) + 1.f);
            pr += w1.z * __builtin_amdgcn_rcpf(__builtin_exp2f(fmaf(bf_lo(av.w), C2, bc6)) + 1.f);
            pr += w1.w * __builtin_amdgcn_rcpf(__builtin_exp2f(fmaf(bf_hi(av.w), C2, bc7)) + 1.f);
            pr += __shfl_xor(pr, 1);
            pr += __shfl_xor(pr, 2);
            pr += __shfl_xor(pr, 4);
            pr += __shfl_xor(pr, 8);
            float p = sumw - 2.f * pr;                    // edge score e
            float ex = (my < cend) ? __builtin_exp2f(fmaf(p, L2E, negswl)) : 0.f;
            ssum += ex;
            acc[0] = fmaf(ex, bf_lo(fv.x), acc[0]);
            acc[1] = fmaf(ex, bf_hi(fv.x), acc[1]);
            acc[2] = fmaf(ex, bf_lo(fv.y), acc[2]);
            acc[3] = fmaf(ex, bf_hi(fv.y), acc[3]);
            acc[4] = fmaf(ex, bf_lo(fv.z), acc[4]);
            acc[5] = fmaf(ex, bf_hi(fv.z), acc[5]);
            acc[6] = fmaf(ex, bf_lo(fv.w), acc[6]);
            acc[7] = fmaf(ex, bf_hi(fv.w), acc[7]);
        }
    }
    ssum += __shfl_xor(ssum, 16);
    ssum += __shfl_xor(ssum, 32);
    #pragma unroll
    for (int j = 0; j < 8; ++j) {
        acc[j] += __shfl_xor(acc[j], 16);
        acc[j] += __shfl_xor(acc[j], 32);
    }
    float inv = __builtin_amdgcn_rcpf(ssum);
    if (eg == 0) {
        *(float4*)(outp + fl * 8) =
            make_float4(acc[0] * inv, acc[1] * inv, acc[2] * inv, acc[3] * inv);
        *(float4*)(outp + fl * 8 + 4) =
            make_float4(acc[4] * inv, acc[5] * inv, acc[6] * inv, acc[7] * inv);
    }
}

extern "C" void kernel_launch(void* const* d_in, const int* in_sizes, int n_in,
                              void* d_out, int out_size, void* d_ws, size_t ws_size,
                              hipStream_t stream) {
    const float* feat = (const float*)d_in[0];
    const int*   src  = (const int*)d_in[1];
    const int*   dst  = (const int*)d_in[2];
    const float* W    = (const float*)d_in[3];
    const float* bvec = (const float*)d_in[4];
    const float* wout = (const float*)d_in[5];
    float* out = (float*)d_out;

    const int N = in_sizes[0] / F;
    const int S = in_sizes[3] / (2 * F * F);
    const int E = in_sizes[1] / S;
    const int SE = S * E;
    const int BPS = (N + 255) / 256;
    const int NB  = (N + 255) >> 8;
    const int NBS = NB * S;
    const bool packed = (N <= 65536) && (NBS <= 1024) && (S * BPS <= 1024);

    size_t fixed = (size_t)N * 64 * 4            // feat16
                 + (size_t)S * 32768 * 2         // Wt (bf16, transposed)
                 + (size_t)SE * 4                // src_csr
                 + (size_t)SE * 4                // recs
                 + (size_t)S * N * 4             // cnt
                 + (size_t)S * (N + 1) * 4       // row_off
                 + (size_t)S * BPS * 4 * 2       // partials + scanned
                 + (size_t)(NBS + 1) * 4 * 3;    // bkt_cnt/off/cur
    size_t perB = (size_t)N * 64 * 4 * 2;        // a16 + bp16
    const int B = (ws_size >= fixed + perB * (size_t)S + 1024) ? S : 1;

    char* p = (char*)d_ws;
    unsigned* feat16   = (unsigned*)p;        p += (size_t)N * 64 * 4;
    unsigned* a16      = (unsigned*)p;        p += (size_t)B * N * 64 * 4;
    unsigned* bp16     = (unsigned*)p;        p += (size_t)B * N * 64 * 4;
    unsigned short* Wt = (unsigned short*)p;  p += (size_t)S * 32768 * 2;
    int*      src_csr  = (int*)p;             p += (size_t)SE * 4;
    unsigned* recs     = (unsigned*)p;        p += (size_t)SE * 4;
    int*      cnt      = (int*)p;             p += (size_t)S * N * 4;
    int*      row_off  = (int*)p;             p += (size_t)S * (N + 1) * 4;
    int*      partials = (int*)p;             p += (size_t)S * BPS * 4;
    int*      scanned  = (int*)p;             p += (size_t)S * BPS * 4;
    int*      bkt_cnt  = (int*)p;             p += (size_t)(NBS + 1) * 4;
    int*      bkt_off  = (int*)p;             p += (size_t)(NBS + 1) * 4;
    int*      bkt_cur  = (int*)p;

    const int n4 = N * F / 4;
    const int proj_blocks = (N + 63) / 64;
    const int node_blocks = (N + 3) / 4;
    const int se_blocks   = (SE + 255) / 256;
    const int wt_total    = S * 256 * 128;

    cvt_feat_kernel<<<2048, 256, 0, stream>>>(feat, feat16, n4);
    cvt_w_kernel<<<(wt_total + 255) / 256, 256, 0, stream>>>(W, Wt, wt_total);

    if (packed) {
        hipMemsetAsync(bkt_cnt, 0, (size_t)NBS * sizeof(int), stream);
        bucket_count_kernel<<<256, 256, 0, stream>>>(dst, bkt_cnt, E, SE, NB, NBS);
        bucket_scan_kernel<<<1, 1024, 0, stream>>>(bkt_cnt, bkt_off, bkt_cur, NBS);
        bucket_scatter_kernel<<<256, 256, 0, stream>>>(src, dst, bkt_cur, recs,
                                                       E, SE, NB, NBS);
        node_count_bucket_kernel<<<NBS, 256, 0, stream>>>(recs, bkt_off, cnt, N, NB);
        partial_kernel<<<dim3(BPS, S), 256, 0, stream>>>(cnt, partials, N, BPS);
        scan_partials_kernel<<<1, 1024, 0, stream>>>(partials, scanned, row_off,
                                                     S, BPS, N);
        emit_kernel<<<dim3(BPS, S), 256, 0, stream>>>(cnt, scanned, row_off, N, BPS);
        csr_fill_bucket_kernel<<<NBS, 256, 0, stream>>>(recs, bkt_off, row_off,
                                                        src_csr, N, E, NB);
    } else {
        hipMemsetAsync(cnt, 0, (size_t)S * N * sizeof(int), stream);
        count_all_kernel<<<se_blocks, 256, 0, stream>>>(dst, cnt, E, SE, N);
        partial_kernel<<<dim3(BPS, S), 256, 0, stream>>>(cnt, partials, N, BPS);
        scan_partials_kernel<<<1, 1024, 0, stream>>>(partials, scanned, row_off,
                                                     S, BPS, N);
        emit_kernel<<<dim3(BPS, S), 256, 0, stream>>>(cnt, scanned, row_off, N, BPS);
        emit_cursor_kernel<<<dim3(BPS, S), 256, 0, stream>>>(row_off, cnt, N);
        fill_all_kernel<<<se_blocks, 256, 0, stream>>>(src, dst, cnt, src_csr,
                                                       E, SE, N);
    }

    for (int k0 = 0; k0 < S; k0 += B) {
        proj_mfma_kernel<<<dim3(proj_blocks, B), 256, 0, stream>>>(
            (const unsigned short*)feat16, Wt, bvec,
            (unsigned short*)a16, (unsigned short*)bp16, N, k0);
        fused_kernel<<<dim3(node_blocks, B), 256, 0, stream>>>(
            (const uint4*)feat16, (const uint4*)a16, (const uint4*)bp16, wout,
            src_csr, row_off, out, N, S, E, k0);
    }
}

// Round 7
// 468.495 us; speedup vs baseline: 4.0618x; 1.0365x over previous
//
#include <hip/hip_runtime.h>
#include <hip/hip_bf16.h>

// AngleOrientedConv: per space k (S=4):
//   a  = feat @ W[k][:128,:];  bp = feat @ W[k][128:,:] + b[k]
//   e  = sum_j tanh(a[src][j] + bp[dst][j]) * w[k][j]
//   segment softmax over dst; out[:, k*128:(k+1)*128] = sum alpha * feat[src]
//
// Round 7: fused kernel is gather-bound (252us invariant to VALU halving,
// FETCH invariant). Add depth-1 software pipeline: issue next edge-group's
// a16/feat16 gathers before computing current group -> load latency hides
// under the exp/shfl chain. Aux: wider grids for bucket count/scatter.

#define F 128

typedef __attribute__((ext_vector_type(8))) short short8v;   // 8 bf16
typedef __attribute__((ext_vector_type(4))) float f32x4;

__device__ __forceinline__ unsigned f2bf(float x) {  // round-to-nearest-even
    unsigned u = __float_as_uint(x);
    unsigned r = ((u >> 16) & 1u) + 0x7fffu;
    return (u + r) >> 16;
}
__device__ __forceinline__ float bf_lo(unsigned v) { return __uint_as_float(v << 16); }
__device__ __forceinline__ float bf_hi(unsigned v) { return __uint_as_float(v & 0xffff0000u); }

// ---------------- feat -> bf16 (once) ----------------
__global__ __launch_bounds__(256) void cvt_feat_kernel(
    const float* __restrict__ feat, unsigned* __restrict__ feat16, int n4)
{
    for (int i = blockIdx.x * 256 + threadIdx.x; i < n4; i += gridDim.x * 256) {
        float4 v = *(const float4*)(feat + (size_t)i * 4);
        unsigned lo = f2bf(v.x) | (f2bf(v.y) << 16);
        unsigned hi = f2bf(v.z) | (f2bf(v.w) << 16);
        *(uint2*)(feat16 + (size_t)i * 2) = make_uint2(lo, hi);
    }
}

// ---------------- W -> transposed bf16: Wt[s][c(256)][k(128)] ----------------
__global__ __launch_bounds__(256) void cvt_w_kernel(
    const float* __restrict__ W, unsigned short* __restrict__ Wt, int total)
{
    int tid = blockIdx.x * 256 + threadIdx.x;
    if (tid >= total) return;
    int i = tid & 127;
    int c = (tid >> 7) & 255;
    int s = tid >> 15;
    float v = W[(size_t)s * 32768 + (size_t)(((c >> 7) << 7) + i) * 128 + (c & 127)];
    Wt[tid] = (unsigned short)f2bf(v);
}

// ---------------- proj via MFMA: [a||bp](bf16) = feat16 @ Wt^T + bias -------
__global__ __launch_bounds__(256) void proj_mfma_kernel(
    const unsigned short* __restrict__ feat16s,
    const unsigned short* __restrict__ WtAll,
    const float* __restrict__ bvec,
    unsigned short* __restrict__ a16s, unsigned short* __restrict__ bp16s,
    int N, int k0)
{
    const int t = threadIdx.x;
    const int w = t >> 6, l = t & 63;
    const int by = blockIdx.y, k = k0 + by;
    const int row0 = blockIdx.x * 64 + w * 16;
    const unsigned short* Wk = WtAll + (size_t)k * 256 * 128;

    const int lrow = l & 15;
    const int lk = (l >> 4) * 8;

    f32x4 acc[16];
    #pragma unroll
    for (int jt = 0; jt < 16; ++jt) acc[jt] = (f32x4){0.f, 0.f, 0.f, 0.f};

    const int arow = row0 + lrow;
    const bool aok = arow < N;
    const unsigned short* ap = feat16s + (size_t)arow * 128 + lk;

    #pragma unroll
    for (int kk = 0; kk < 4; ++kk) {
        short8v af = {0, 0, 0, 0, 0, 0, 0, 0};
        if (aok) af = *(const short8v*)(ap + kk * 32);
        #pragma unroll
        for (int jt = 0; jt < 16; ++jt) {
            short8v bf = *(const short8v*)(Wk + (size_t)(jt * 16 + lrow) * 128 + kk * 32 + lk);
            acc[jt] = __builtin_amdgcn_mfma_f32_16x16x32_bf16(af, bf, acc[jt], 0, 0, 0);
        }
    }

    unsigned short* a16k  = a16s  + (size_t)by * N * 128;
    unsigned short* bp16k = bp16s + (size_t)by * N * 128;
    #pragma unroll
    for (int jt = 0; jt < 16; ++jt) {
        const int col = jt * 16 + lrow;
        const int c = col & 127;
        const bool isb = (jt >= 8);
        float bias = isb ? bvec[(size_t)k * F + c] : 0.f;
        unsigned short* dstp = isb ? bp16k : a16k;
        #pragma unroll
        for (int r = 0; r < 4; ++r) {
            int node = row0 + (l >> 4) * 4 + r;
            if (node < N)
                dstp[(size_t)node * 128 + c] = (unsigned short)f2bf(acc[jt][r] + bias);
        }
    }
}

// ============= bucket-binned CSR build (N <= 65536 path) =============
__global__ __launch_bounds__(256) void bucket_count_kernel(
    const int* __restrict__ dst, int* __restrict__ bkt_cnt,
    int E, int SE, int NB, int NBS)
{
    __shared__ int hist[1024];
    const int t = threadIdx.x;
    for (int i = t; i < NBS; i += 256) hist[i] = 0;
    __syncthreads();
    const int chunk = (SE + gridDim.x - 1) / gridDim.x;
    const int e0 = blockIdx.x * chunk;
    const int e1 = min(SE, e0 + chunk);
    for (int e = e0 + t; e < e1; e += 256) {
        int s = e / E;
        atomicAdd(&hist[s * NB + (dst[e] >> 8)], 1);
    }
    __syncthreads();
    for (int i = t; i < NBS; i += 256)
        if (hist[i]) atomicAdd(&bkt_cnt[i], hist[i]);
}

__global__ __launch_bounds__(1024) void bucket_scan_kernel(
    const int* __restrict__ bkt_cnt, int* __restrict__ bkt_off,
    int* __restrict__ bkt_cur, int NBS)
{
    __shared__ int buf[1024];
    const int t = threadIdx.x;
    buf[t] = (t < NBS) ? bkt_cnt[t] : 0;
    __syncthreads();
    for (int off = 1; off < 1024; off <<= 1) {
        int x = (t >= off) ? buf[t - off] : 0;
        __syncthreads();
        buf[t] += x;
        __syncthreads();
    }
    if (t <= NBS) {
        int v = (t == 0) ? 0 : buf[t - 1];
        bkt_off[t] = v;
        if (t < NBS) bkt_cur[t] = v;
    }
}

__global__ __launch_bounds__(256) void bucket_scatter_kernel(
    const int* __restrict__ src, const int* __restrict__ dst,
    int* __restrict__ bkt_cur, unsigned* __restrict__ recs,
    int E, int SE, int NB, int NBS)
{
    __shared__ int hist[1024];
    __shared__ int base[1024];
    const int t = threadIdx.x;
    for (int i = t; i < NBS; i += 256) hist[i] = 0;
    __syncthreads();
    const int chunk = (SE + gridDim.x - 1) / gridDim.x;
    const int e0 = blockIdx.x * chunk;
    const int e1 = min(SE, e0 + chunk);
    for (int e = e0 + t; e < e1; e += 256) {
        int s = e / E;
        atomicAdd(&hist[s * NB + (dst[e] >> 8)], 1);
    }
    __syncthreads();
    for (int i = t; i < NBS; i += 256) {
        int h = hist[i];
        if (h) base[i] = atomicAdd(&bkt_cur[i], h);
        hist[i] = 0;
    }
    __syncthreads();
    for (int e = e0 + t; e < e1; e += 256) {
        int s = e / E;
        int d = dst[e];
        int gb = s * NB + (d >> 8);
        int lo = atomicAdd(&hist[gb], 1);
        recs[base[gb] + lo] = (unsigned)src[e] | ((unsigned)(d & 255) << 16);
    }
}

__global__ __launch_bounds__(256) void node_count_bucket_kernel(
    const unsigned* __restrict__ recs, const int* __restrict__ bkt_off,
    int* __restrict__ cnt, int N, int NB)
{
    __shared__ int hist[256];
    const int t = threadIdx.x;
    const int gb = blockIdx.x;
    const int s = gb / NB;
    const int node0 = (gb % NB) << 8;
    hist[t] = 0;
    __syncthreads();
    const int r0 = bkt_off[gb], r1 = bkt_off[gb + 1];
    for (int r = r0 + t; r < r1; r += 256)
        atomicAdd(&hist[(recs[r] >> 16) & 255], 1);
    __syncthreads();
    int node = node0 + t;
    if (node < N) cnt[(size_t)s * N + node] = hist[t];
}

__global__ __launch_bounds__(256) void partial_kernel(
    const int* __restrict__ cnt, int* __restrict__ partials, int N, int BPS)
{
    __shared__ int red[256];
    const int s = blockIdx.y, b = blockIdx.x, t = threadIdx.x;
    int i = b * 256 + t;
    red[t] = (i < N) ? cnt[(size_t)s * N + i] : 0;
    __syncthreads();
    #pragma unroll
    for (int off = 128; off; off >>= 1) {
        if (t < off) red[t] += red[t + off];
        __syncthreads();
    }
    if (t == 0) partials[s * BPS + b] = red[0];
}

__global__ __launch_bounds__(1024) void scan_partials_kernel(
    const int* __restrict__ partials, int* __restrict__ scanned,
    int* __restrict__ row_off, int S, int BPS, int N)
{
    __shared__ int buf[1024];
    const int t = threadIdx.x;
    const int total = S * BPS;
    buf[t] = (t < total) ? partials[t] : 0;
    __syncthreads();
    for (int off = 1; off < 1024; off <<= 1) {
        int x = (t >= off) ? buf[t - off] : 0;
        __syncthreads();
        buf[t] += x;
        __syncthreads();
    }
    if (t < total) {
        int s = t / BPS;
        int g_excl = (t == 0) ? 0 : buf[t - 1];
        int base = (s == 0) ? 0 : buf[s * BPS - 1];
        scanned[t] = g_excl - base;
    }
    if (t < S) {
        int end  = buf[(t + 1) * BPS - 1];
        int base = (t == 0) ? 0 : buf[t * BPS - 1];
        row_off[(size_t)t * (N + 1) + N] = end - base;
    }
}

__global__ __launch_bounds__(256) void emit_kernel(
    const int* __restrict__ cnt, const int* __restrict__ scanned,
    int* __restrict__ row_off, int N, int BPS)
{
    __shared__ int buf[256];
    const int s = blockIdx.y, b = blockIdx.x, t = threadIdx.x;
    int i = b * 256 + t;
    int v = (i < N) ? cnt[(size_t)s * N + i] : 0;
    buf[t] = v;
    __syncthreads();
    for (int off = 1; off < 256; off <<= 1) {
        int x = (t >= off) ? buf[t - off] : 0;
        __syncthreads();
        buf[t] += x;
        __syncthreads();
    }
    if (i < N)
        row_off[(size_t)s * (N + 1) + i] = scanned[s * BPS + b] + buf[t] - v;
}

__global__ __launch_bounds__(256) void csr_fill_bucket_kernel(
    const unsigned* __restrict__ recs, const int* __restrict__ bkt_off,
    const int* __restrict__ row_off, int* __restrict__ src_csr,
    int N, int E, int NB)
{
    __shared__ int cur[256];
    const int t = threadIdx.x;
    const int gb = blockIdx.x;
    const int s = gb / NB;
    const int node0 = (gb % NB) << 8;
    int node = node0 + t;
    cur[t] = (node < N) ? row_off[(size_t)s * (N + 1) + node] : 0;
    __syncthreads();
    int* csr = src_csr + (size_t)s * E;
    const int r0 = bkt_off[gb], r1 = bkt_off[gb + 1];
    for (int r = r0 + t; r < r1; r += 256) {
        unsigned rec = recs[r];
        int pos = atomicAdd(&cur[(rec >> 16) & 255], 1);
        csr[pos] = (int)(rec & 0xFFFFu);
    }
}

// ============= fallback CSR build (N > 65536) =============
__global__ __launch_bounds__(256) void count_all_kernel(
    const int* __restrict__ dst, int* __restrict__ cnt, int E, int SE, int N)
{
    int e = blockIdx.x * 256 + threadIdx.x;
    if (e < SE) {
        int s = e / E;
        atomicAdd(&cnt[(size_t)s * N + dst[e]], 1);
    }
}
__global__ __launch_bounds__(256) void emit_cursor_kernel(
    const int* __restrict__ row_off, int* __restrict__ cursor, int N)
{
    const int s = blockIdx.y;
    int i = blockIdx.x * 256 + threadIdx.x;
    if (i < N) cursor[(size_t)s * N + i] = row_off[(size_t)s * (N + 1) + i];
}
__global__ __launch_bounds__(256) void fill_all_kernel(
    const int* __restrict__ src, const int* __restrict__ dst,
    int* __restrict__ cursor, int* __restrict__ src_csr,
    int E, int SE, int N)
{
    int e = blockIdx.x * 256 + threadIdx.x;
    if (e < SE) {
        int s = e / E;
        int pos = atomicAdd(&cursor[(size_t)s * N + dst[e]], 1);
        src_csr[(size_t)s * E + pos] = src[e];
    }
}

// ------------- fused single-pass attention+softmax+gather (pipelined) -------
// wave per dst node; 16 lanes per edge, 4 edges per group; depth-1 prefetch
// of the next group's a16/feat16 gathers. No max pass (|e| <= sum|w| bound).
__global__ __launch_bounds__(256) void fused_kernel(
    const uint4* __restrict__ feat16, const uint4* __restrict__ a16,
    const uint4* __restrict__ bp16, const float* __restrict__ wout,
    const int* __restrict__ src_csr_all, const int* __restrict__ row_off_all,
    float* __restrict__ out, int N, int S, int E, int k0)
{
    const int by = blockIdx.y, k = k0 + by;
    const int wslot = threadIdx.x >> 6;
    const int node = blockIdx.x * 4 + wslot;
    const int lane = threadIdx.x & 63;
    const int eg = lane >> 4;
    const int fl = lane & 15;
    if (node >= N) return;

    const int* row_off = row_off_all + (size_t)k * (N + 1);
    const int* src_csr = src_csr_all + (size_t)k * E;
    const uint4* a16k  = a16  + (size_t)by * N * 16;
    const uint4* bp16k = bp16 + (size_t)by * N * 16;

    const int beg = row_off[node];
    const int cnt = row_off[node + 1] - beg;
    float* outp = out + (size_t)node * (S * F) + k * F;
    if (cnt == 0) {
        if (eg == 0) {
            *(float4*)(outp + fl * 8)     = make_float4(0.f, 0.f, 0.f, 0.f);
            *(float4*)(outp + fl * 8 + 4) = make_float4(0.f, 0.f, 0.f, 0.f);
        }
        return;
    }

    const float C2  = 2.8853900817779268f;   // 2*log2(e)
    const float L2E = 1.4426950408889634f;

    uint4 bv = bp16k[(size_t)node * 16 + fl];
    const float bc0 = bf_lo(bv.x) * C2, bc1 = bf_hi(bv.x) * C2;
    const float bc2 = bf_lo(bv.y) * C2, bc3 = bf_hi(bv.y) * C2;
    const float bc4 = bf_lo(bv.z) * C2, bc5 = bf_hi(bv.z) * C2;
    const float bc6 = bf_lo(bv.w) * C2, bc7 = bf_hi(bv.w) * C2;
    const float4* w4 = (const float4*)(wout + (size_t)k * F);
    const float4 w0 = w4[fl * 2];
    const float4 w1 = w4[fl * 2 + 1];

    float sumw = w0.x + w0.y + w0.z + w0.w + w1.x + w1.y + w1.z + w1.w;
    float sabs = fabsf(w0.x) + fabsf(w0.y) + fabsf(w0.z) + fabsf(w0.w)
               + fabsf(w1.x) + fabsf(w1.y) + fabsf(w1.z) + fabsf(w1.w);
    #pragma unroll
    for (int off = 1; off < 16; off <<= 1) {
        sumw += __shfl_xor(sumw, off);
        sabs += __shfl_xor(sabs, off);
    }
    const float negswl = -sabs * L2E;   // softmax shift (in log2 domain)

    const int ngroups = (cnt + 3) >> 2;

    // chunk 0 src indices + group 0 prefetch
    int sv = (lane < cnt) ? src_csr[beg + lane] : 0;
    int sj = __shfl(sv, eg);
    size_t gbase = (size_t)sj * 16 + fl;
    uint4 av0 = a16k[gbase];
    uint4 fv0 = feat16[gbase];

    float ssum = 0.f;
    float acc[8] = {0.f, 0.f, 0.f, 0.f, 0.f, 0.f, 0.f, 0.f};

    for (int g = 0; g < ngroups; ++g) {
        const int q = g * 4;
        // ---- prefetch group g+1 ----
        uint4 av1, fv1;
        const bool have_next = (g + 1) < ngroups;
        if (have_next) {
            int qn = q + 4;
            if ((qn & 63) == 0) {             // next 64-edge chunk of src ids
                int idx = qn + lane;
                sv = (idx < cnt) ? src_csr[beg + idx] : 0;
            }
            int sjn = __shfl(sv, (qn & 63) + eg);
            size_t nbase = (size_t)sjn * 16 + fl;
            av1 = a16k[nbase];
            fv1 = feat16[nbase];
        }
        // ---- compute group g with av0/fv0 ----
        float pr;
        pr  = w0.x * __builtin_amdgcn_rcpf(__builtin_exp2f(fmaf(bf_lo(av0.x), C2, bc0)) + 1.f);
        pr += w0.y * __builtin_amdgcn_rcpf(__builtin_exp2f(fmaf(bf_hi(av0.x), C2, bc1)) + 1.f);
        pr += w0.z * __builtin_amdgcn_rcpf(__builtin_exp2f(fmaf(bf_lo(av0.y), C2, bc2)) + 1.f);
        pr += w0.w * __builtin_amdgcn_rcpf(__builtin_exp2f(fmaf(bf_hi(av0.y), C2, bc3)) + 1.f);
        pr += w1.x * __builtin_amdgcn_rcpf(__builtin_exp2f(fmaf(bf_lo(av0.z), C2, bc4)) + 1.f);
        pr += w1.y * __builtin_amdgcn_rcpf(__builtin_exp2f(fmaf(bf_hi(av0.z), C2, bc5)) + 1.f);
        pr += w1.z * __builtin_amdgcn_rcpf(__builtin_exp2f(fmaf(bf_lo(av0.w), C2, bc6)) + 1.f);
        pr += w1.w * __builtin_amdgcn_rcpf(__builtin_exp2f(fmaf(bf_hi(av0.w), C2, bc7)) + 1.f);
        pr += __shfl_xor(pr, 1);
        pr += __shfl_xor(pr, 2);
        pr += __shfl_xor(pr, 4);
        pr += __shfl_xor(pr, 8);
        float p = sumw - 2.f * pr;                    // edge score e
        float ex = ((q + eg) < cnt) ? __builtin_exp2f(fmaf(p, L2E, negswl)) : 0.f;
        ssum += ex;
        acc[0] = fmaf(ex, bf_lo(fv0.x), acc[0]);
        acc[1] = fmaf(ex, bf_hi(fv0.x), acc[1]);
        acc[2] = fmaf(ex, bf_lo(fv0.y), acc[2]);
        acc[3] = fmaf(ex, bf_hi(fv0.y), acc[3]);
        acc[4] = fmaf(ex, bf_lo(fv0.z), acc[4]);
        acc[5] = fmaf(ex, bf_hi(fv0.z), acc[5]);
        acc[6] = fmaf(ex, bf_lo(fv0.w), acc[6]);
        acc[7] = fmaf(ex, bf_hi(fv0.w), acc[7]);
        av0 = av1;
        fv0 = fv1;
    }

    ssum += __shfl_xor(ssum, 16);
    ssum += __shfl_xor(ssum, 32);
    #pragma unroll
    for (int j = 0; j < 8; ++j) {
        acc[j] += __shfl_xor(acc[j], 16);
        acc[j] += __shfl_xor(acc[j], 32);
    }
    float inv = __builtin_amdgcn_rcpf(ssum);
    if (eg == 0) {
        *(float4*)(outp + fl * 8) =
            make_float4(acc[0] * inv, acc[1] * inv, acc[2] * inv, acc[3] * inv);
        *(float4*)(outp + fl * 8 + 4) =
            make_float4(acc[4] * inv, acc[5] * inv, acc[6] * inv, acc[7] * inv);
    }
}

extern "C" void kernel_launch(void* const* d_in, const int* in_sizes, int n_in,
                              void* d_out, int out_size, void* d_ws, size_t ws_size,
                              hipStream_t stream) {
    const float* feat = (const float*)d_in[0];
    const int*   src  = (const int*)d_in[1];
    const int*   dst  = (const int*)d_in[2];
    const float* W    = (const float*)d_in[3];
    const float* bvec = (const float*)d_in[4];
    const float* wout = (const float*)d_in[5];
    float* out = (float*)d_out;

    const int N = in_sizes[0] / F;
    const int S = in_sizes[3] / (2 * F * F);
    const int E = in_sizes[1] / S;
    const int SE = S * E;
    const int BPS = (N + 255) / 256;
    const int NB  = (N + 255) >> 8;
    const int NBS = NB * S;
    const bool packed = (N <= 65536) && (NBS <= 1024) && (S * BPS <= 1024);

    size_t fixed = (size_t)N * 64 * 4            // feat16
                 + (size_t)S * 32768 * 2         // Wt (bf16, transposed)
                 + (size_t)SE * 4                // src_csr
                 + (size_t)SE * 4                // recs
                 + (size_t)S * N * 4             // cnt
                 + (size_t)S * (N + 1) * 4       // row_off
                 + (size_t)S * BPS * 4 * 2       // partials + scanned
                 + (size_t)(NBS + 1) * 4 * 3;    // bkt_cnt/off/cur
    size_t perB = (size_t)N * 64 * 4 * 2;        // a16 + bp16
    const int B = (ws_size >= fixed + perB * (size_t)S + 1024) ? S : 1;

    char* p = (char*)d_ws;
    unsigned* feat16   = (unsigned*)p;        p += (size_t)N * 64 * 4;
    unsigned* a16      = (unsigned*)p;        p += (size_t)B * N * 64 * 4;
    unsigned* bp16     = (unsigned*)p;        p += (size_t)B * N * 64 * 4;
    unsigned short* Wt = (unsigned short*)p;  p += (size_t)S * 32768 * 2;
    int*      src_csr  = (int*)p;             p += (size_t)SE * 4;
    unsigned* recs     = (unsigned*)p;        p += (size_t)SE * 4;
    int*      cnt      = (int*)p;             p += (size_t)S * N * 4;
    int*      row_off  = (int*)p;             p += (size_t)S * (N + 1) * 4;
    int*      partials = (int*)p;             p += (size_t)S * BPS * 4;
    int*      scanned  = (int*)p;             p += (size_t)S * BPS * 4;
    int*      bkt_cnt  = (int*)p;             p += (size_t)(NBS + 1) * 4;
    int*      bkt_off  = (int*)p;             p += (size_t)(NBS + 1) * 4;
    int*      bkt_cur  = (int*)p;

    const int n4 = N * F / 4;
    const int proj_blocks = (N + 63) / 64;
    const int node_blocks = (N + 3) / 4;
    const int se_blocks   = (SE + 255) / 256;
    const int wt_total    = S * 256 * 128;

    cvt_feat_kernel<<<2048, 256, 0, stream>>>(feat, feat16, n4);
    cvt_w_kernel<<<(wt_total + 255) / 256, 256, 0, stream>>>(W, Wt, wt_total);

    if (packed) {
        hipMemsetAsync(bkt_cnt, 0, (size_t)NBS * sizeof(int), stream);
        bucket_count_kernel<<<512, 256, 0, stream>>>(dst, bkt_cnt, E, SE, NB, NBS);
        bucket_scan_kernel<<<1, 1024, 0, stream>>>(bkt_cnt, bkt_off, bkt_cur, NBS);
        bucket_scatter_kernel<<<512, 256, 0, stream>>>(src, dst, bkt_cur, recs,
                                                       E, SE, NB, NBS);
        node_count_bucket_kernel<<<NBS, 256, 0, stream>>>(recs, bkt_off, cnt, N, NB);
        partial_kernel<<<dim3(BPS, S), 256, 0, stream>>>(cnt, partials, N, BPS);
        scan_partials_kernel<<<1, 1024, 0, stream>>>(partials, scanned, row_off,
                                                     S, BPS, N);
        emit_kernel<<<dim3(BPS, S), 256, 0, stream>>>(cnt, scanned, row_off, N, BPS);
        csr_fill_bucket_kernel<<<NBS, 256, 0, stream>>>(recs, bkt_off, row_off,
                                                        src_csr, N, E, NB);
    } else {
        hipMemsetAsync(cnt, 0, (size_t)S * N * sizeof(int), stream);
        count_all_kernel<<<se_blocks, 256, 0, stream>>>(dst, cnt, E, SE, N);
        partial_kernel<<<dim3(BPS, S), 256, 0, stream>>>(cnt, partials, N, BPS);
        scan_partials_kernel<<<1, 1024, 0, stream>>>(partials, scanned, row_off,
                                                     S, BPS, N);
        emit_kernel<<<dim3(BPS, S), 256, 0, stream>>>(cnt, scanned, row_off, N, BPS);
        emit_cursor_kernel<<<dim3(BPS, S), 256, 0, stream>>>(row_off, cnt, N);
        fill_all_kernel<<<se_blocks, 256, 0, stream>>>(src, dst, cnt, src_csr,
                                                       E, SE, N);
    }

    for (int k0 = 0; k0 < S; k0 += B) {
        proj_mfma_kernel<<<dim3(proj_blocks, B), 256, 0, stream>>>(
            (const unsigned short*)feat16, Wt, bvec,
            (unsigned short*)a16, (unsigned short*)bp16, N, k0);
        fused_kernel<<<dim3(node_blocks, B), 256, 0, stream>>>(
            (const uint4*)feat16, (const uint4*)a16, (const uint4*)bp16, wout,
            src_csr, row_off, out, N, S, E, k0);
    }
}

// Round 8
// 368.074 us; speedup vs baseline: 5.1700x; 1.2728x over previous
//
#include <hip/hip_runtime.h>
#include <hip/hip_bf16.h>

// AngleOrientedConv: per space k (S=4):
//   a  = feat @ W[k][:128,:];  bp = feat @ W[k][128:,:] + b[k]
//   e  = sum_j tanh(a[src][j] + bp[dst][j]) * w[k][j]
//   segment softmax over dst; out[:, k*128:(k+1)*128] = sum alpha * feat[src]
//
// Round 8: fused kernel is L2-miss-BW bound (FETCH/dur invariant across VALU
// halving and prefetch). Reduce miss bytes: a stored as fp8 e4m3 (HW cvt,
// 128B/edge gather = 1 line), permuted a8/bp16 layout for vector stores and
// lane-local decode. Proj: Wk staged in LDS (XOR-swizzled) to kill ~800MB of
// global B re-reads; vectorized epilogue.

#define F 128

typedef __attribute__((ext_vector_type(8))) short short8v;   // 8 bf16
typedef __attribute__((ext_vector_type(4))) float f32x4;
typedef __attribute__((ext_vector_type(2))) float f32x2;

__device__ __forceinline__ unsigned f2bf(float x) {  // round-to-nearest-even
    unsigned u = __float_as_uint(x);
    unsigned r = ((u >> 16) & 1u) + 0x7fffu;
    return (u + r) >> 16;
}
__device__ __forceinline__ float bf_lo(unsigned v) { return __uint_as_float(v << 16); }
__device__ __forceinline__ float bf_hi(unsigned v) { return __uint_as_float(v & 0xffff0000u); }

// ---------------- feat -> bf16 (once) ----------------
__global__ __launch_bounds__(256) void cvt_feat_kernel(
    const float* __restrict__ feat, unsigned* __restrict__ feat16, int n4)
{
    for (int i = blockIdx.x * 256 + threadIdx.x; i < n4; i += gridDim.x * 256) {
        float4 v = *(const float4*)(feat + (size_t)i * 4);
        unsigned lo = f2bf(v.x) | (f2bf(v.y) << 16);
        unsigned hi = f2bf(v.z) | (f2bf(v.w) << 16);
        *(uint2*)(feat16 + (size_t)i * 2) = make_uint2(lo, hi);
    }
}

// ---------------- W -> transposed bf16: Wt[s][c(256)][k(128)] ----------------
__global__ __launch_bounds__(256) void cvt_w_kernel(
    const float* __restrict__ W, unsigned short* __restrict__ Wt, int total)
{
    int tid = blockIdx.x * 256 + threadIdx.x;
    if (tid >= total) return;
    int i = tid & 127;
    int c = (tid >> 7) & 255;
    int s = tid >> 15;
    float v = W[(size_t)s * 32768 + (size_t)(((c >> 7) << 7) + i) * 128 + (c & 127)];
    Wt[tid] = (unsigned short)f2bf(v);
}

// ---------------- proj via MFMA, Wk in LDS (swizzled) ----------------------
// a8[node][p]  (fp8): feature j=(p&7)*16+(p>>3)  stored at p = lrow*8 + jt
// bp16[node][p](bf16): feature j=(p&7)*16+(p>>3) stored at p = lrow*8 + (jt-8)
__global__ __launch_bounds__(256) void proj_mfma_kernel(
    const unsigned short* __restrict__ feat16s,
    const unsigned short* __restrict__ WtAll,
    const float* __restrict__ bvec,
    unsigned char* __restrict__ a8, unsigned short* __restrict__ bp16s,
    int N, int k0)
{
    __shared__ uint4 wlds4[4096];   // 64 KB: Wk staged, 16B-unit XOR swizzle
    const int t = threadIdx.x;
    const int w = t >> 6, l = t & 63;
    const int by = blockIdx.y, k = k0 + by;
    const int row0 = blockIdx.x * 64 + w * 16;
    const unsigned short* Wk = WtAll + (size_t)k * 256 * 128;

    // stage Wk: 4096 16B units; unit i belongs to col c = i>>4
    {
        const uint4* Wg = (const uint4*)Wk;
        char* wb = (char*)wlds4;
        for (int i = t; i < 4096; i += 256) {
            int c = i >> 4;
            int swz = (i * 16) ^ ((c & 7) << 4);
            *(uint4*)(wb + swz) = Wg[i];
        }
    }
    __syncthreads();

    const int lrow = l & 15;
    const int rs = l >> 4;
    const int lk = rs * 8;

    f32x4 acc[16];
    #pragma unroll
    for (int jt = 0; jt < 16; ++jt) acc[jt] = (f32x4){0.f, 0.f, 0.f, 0.f};

    const int arow = row0 + lrow;
    const bool aok = arow < N;
    const unsigned short* ap = feat16s + (size_t)arow * 128 + lk;
    const char* wb = (const char*)wlds4;

    #pragma unroll
    for (int kk = 0; kk < 4; ++kk) {
        short8v af = {0, 0, 0, 0, 0, 0, 0, 0};
        if (aok) af = *(const short8v*)(ap + kk * 32);
        #pragma unroll
        for (int jt = 0; jt < 16; ++jt) {
            int c = jt * 16 + lrow;
            int byte = (c * 256 + kk * 64 + rs * 16) ^ ((c & 7) << 4);
            short8v bf = *(const short8v*)(wb + byte);
            acc[jt] = __builtin_amdgcn_mfma_f32_16x16x32_bf16(af, bf, acc[jt], 0, 0, 0);
        }
    }

    unsigned char*  a8k   = a8    + (size_t)by * N * 128;
    unsigned short* bp16k = bp16s + (size_t)by * N * 128;

    float bias[8];
    #pragma unroll
    for (int i = 0; i < 8; ++i) bias[i] = bvec[(size_t)k * F + i * 16 + lrow];

    #pragma unroll
    for (int r = 0; r < 4; ++r) {
        int node = row0 + rs * 4 + r;
        if (node >= N) continue;
        // a-side: 8 fp8 bytes at p = lrow*8 .. +7  (p&7 = jt)
        int w0i = __builtin_amdgcn_cvt_pk_fp8_f32(acc[0][r], acc[1][r], 0, false);
        w0i = __builtin_amdgcn_cvt_pk_fp8_f32(acc[2][r], acc[3][r], w0i, true);
        int w1i = __builtin_amdgcn_cvt_pk_fp8_f32(acc[4][r], acc[5][r], 0, false);
        w1i = __builtin_amdgcn_cvt_pk_fp8_f32(acc[6][r], acc[7][r], w1i, true);
        *(uint2*)(a8k + (size_t)node * 128 + lrow * 8) =
            make_uint2((unsigned)w0i, (unsigned)w1i);
        // bp-side: 8 bf16 at p = lrow*8 .. +7  (p&7 = jt-8), + bias
        uint4 o;
        o.x = f2bf(acc[8][r]  + bias[0]) | (f2bf(acc[9][r]  + bias[1]) << 16);
        o.y = f2bf(acc[10][r] + bias[2]) | (f2bf(acc[11][r] + bias[3]) << 16);
        o.z = f2bf(acc[12][r] + bias[4]) | (f2bf(acc[13][r] + bias[5]) << 16);
        o.w = f2bf(acc[14][r] + bias[6]) | (f2bf(acc[15][r] + bias[7]) << 16);
        *(uint4*)(bp16k + (size_t)node * 128 + lrow * 8) = o;
    }
}

// ============= bucket-binned CSR build (N <= 65536 path) =============
__global__ __launch_bounds__(256) void bucket_count_kernel(
    const int* __restrict__ dst, int* __restrict__ bkt_cnt,
    int E, int SE, int NB, int NBS)
{
    __shared__ int hist[1024];
    const int t = threadIdx.x;
    for (int i = t; i < NBS; i += 256) hist[i] = 0;
    __syncthreads();
    const int chunk = (SE + gridDim.x - 1) / gridDim.x;
    const int e0 = blockIdx.x * chunk;
    const int e1 = min(SE, e0 + chunk);
    for (int e = e0 + t; e < e1; e += 256) {
        int s = e / E;
        atomicAdd(&hist[s * NB + (dst[e] >> 8)], 1);
    }
    __syncthreads();
    for (int i = t; i < NBS; i += 256)
        if (hist[i]) atomicAdd(&bkt_cnt[i], hist[i]);
}

__global__ __launch_bounds__(1024) void bucket_scan_kernel(
    const int* __restrict__ bkt_cnt, int* __restrict__ bkt_off,
    int* __restrict__ bkt_cur, int NBS)
{
    __shared__ int buf[1024];
    const int t = threadIdx.x;
    buf[t] = (t < NBS) ? bkt_cnt[t] : 0;
    __syncthreads();
    for (int off = 1; off < 1024; off <<= 1) {
        int x = (t >= off) ? buf[t - off] : 0;
        __syncthreads();
        buf[t] += x;
        __syncthreads();
    }
    if (t <= NBS) {
        int v = (t == 0) ? 0 : buf[t - 1];
        bkt_off[t] = v;
        if (t < NBS) bkt_cur[t] = v;
    }
}

__global__ __launch_bounds__(256) void bucket_scatter_kernel(
    const int* __restrict__ src, const int* __restrict__ dst,
    int* __restrict__ bkt_cur, unsigned* __restrict__ recs,
    int E, int SE, int NB, int NBS)
{
    __shared__ int hist[1024];
    __shared__ int base[1024];
    const int t = threadIdx.x;
    for (int i = t; i < NBS; i += 256) hist[i] = 0;
    __syncthreads();
    const int chunk = (SE + gridDim.x - 1) / gridDim.x;
    const int e0 = blockIdx.x * chunk;
    const int e1 = min(SE, e0 + chunk);
    for (int e = e0 + t; e < e1; e += 256) {
        int s = e / E;
        atomicAdd(&hist[s * NB + (dst[e] >> 8)], 1);
    }
    __syncthreads();
    for (int i = t; i < NBS; i += 256) {
        int h = hist[i];
        if (h) base[i] = atomicAdd(&bkt_cur[i], h);
        hist[i] = 0;
    }
    __syncthreads();
    for (int e = e0 + t; e < e1; e += 256) {
        int s = e / E;
        int d = dst[e];
        int gb = s * NB + (d >> 8);
        int lo = atomicAdd(&hist[gb], 1);
        recs[base[gb] + lo] = (unsigned)src[e] | ((unsigned)(d & 255) << 16);
    }
}

__global__ __launch_bounds__(256) void node_count_bucket_kernel(
    const unsigned* __restrict__ recs, const int* __restrict__ bkt_off,
    int* __restrict__ cnt, int N, int NB)
{
    __shared__ int hist[256];
    const int t = threadIdx.x;
    const int gb = blockIdx.x;
    const int s = gb / NB;
    const int node0 = (gb % NB) << 8;
    hist[t] = 0;
    __syncthreads();
    const int r0 = bkt_off[gb], r1 = bkt_off[gb + 1];
    for (int r = r0 + t; r < r1; r += 256)
        atomicAdd(&hist[(recs[r] >> 16) & 255], 1);
    __syncthreads();
    int node = node0 + t;
    if (node < N) cnt[(size_t)s * N + node] = hist[t];
}

__global__ __launch_bounds__(256) void partial_kernel(
    const int* __restrict__ cnt, int* __restrict__ partials, int N, int BPS)
{
    __shared__ int red[256];
    const int s = blockIdx.y, b = blockIdx.x, t = threadIdx.x;
    int i = b * 256 + t;
    red[t] = (i < N) ? cnt[(size_t)s * N + i] : 0;
    __syncthreads();
    #pragma unroll
    for (int off = 128; off; off >>= 1) {
        if (t < off) red[t] += red[t + off];
        __syncthreads();
    }
    if (t == 0) partials[s * BPS + b] = red[0];
}

__global__ __launch_bounds__(1024) void scan_partials_kernel(
    const int* __restrict__ partials, int* __restrict__ scanned,
    int* __restrict__ row_off, int S, int BPS, int N)
{
    __shared__ int buf[1024];
    const int t = threadIdx.x;
    const int total = S * BPS;
    buf[t] = (t < total) ? partials[t] : 0;
    __syncthreads();
    for (int off = 1; off < 1024; off <<= 1) {
        int x = (t >= off) ? buf[t - off] : 0;
        __syncthreads();
        buf[t] += x;
        __syncthreads();
    }
    if (t < total) {
        int s = t / BPS;
        int g_excl = (t == 0) ? 0 : buf[t - 1];
        int base = (s == 0) ? 0 : buf[s * BPS - 1];
        scanned[t] = g_excl - base;
    }
    if (t < S) {
        int end  = buf[(t + 1) * BPS - 1];
        int base = (t == 0) ? 0 : buf[t * BPS - 1];
        row_off[(size_t)t * (N + 1) + N] = end - base;
    }
}

__global__ __launch_bounds__(256) void emit_kernel(
    const int* __restrict__ cnt, const int* __restrict__ scanned,
    int* __restrict__ row_off, int N, int BPS)
{
    __shared__ int buf[256];
    const int s = blockIdx.y, b = blockIdx.x, t = threadIdx.x;
    int i = b * 256 + t;
    int v = (i < N) ? cnt[(size_t)s * N + i] : 0;
    buf[t] = v;
    __syncthreads();
    for (int off = 1; off < 256; off <<= 1) {
        int x = (t >= off) ? buf[t - off] : 0;
        __syncthreads();
        buf[t] += x;
        __syncthreads();
    }
    if (i < N)
        row_off[(size_t)s * (N + 1) + i] = scanned[s * BPS + b] + buf[t] - v;
}

__global__ __launch_bounds__(256) void csr_fill_bucket_kernel(
    const unsigned* __restrict__ recs, const int* __restrict__ bkt_off,
    const int* __restrict__ row_off, int* __restrict__ src_csr,
    int N, int E, int NB)
{
    __shared__ int cur[256];
    const int t = threadIdx.x;
    const int gb = blockIdx.x;
    const int s = gb / NB;
    const int node0 = (gb % NB) << 8;
    int node = node0 + t;
    cur[t] = (node < N) ? row_off[(size_t)s * (N + 1) + node] : 0;
    __syncthreads();
    int* csr = src_csr + (size_t)s * E;
    const int r0 = bkt_off[gb], r1 = bkt_off[gb + 1];
    for (int r = r0 + t; r < r1; r += 256) {
        unsigned rec = recs[r];
        int pos = atomicAdd(&cur[(rec >> 16) & 255], 1);
        csr[pos] = (int)(rec & 0xFFFFu);
    }
}

// ============= fallback CSR build (N > 65536) =============
__global__ __launch_bounds__(256) void count_all_kernel(
    const int* __restrict__ dst, int* __restrict__ cnt, int E, int SE, int N)
{
    int e = blockIdx.x * 256 + threadIdx.x;
    if (e < SE) {
        int s = e / E;
        atomicAdd(&cnt[(size_t)s * N + dst[e]], 1);
    }
}
__global__ __launch_bounds__(256) void emit_cursor_kernel(
    const int* __restrict__ row_off, int* __restrict__ cursor, int N)
{
    const int s = blockIdx.y;
    int i = blockIdx.x * 256 + threadIdx.x;
    if (i < N) cursor[(size_t)s * N + i] = row_off[(size_t)s * (N + 1) + i];
}
__global__ __launch_bounds__(256) void fill_all_kernel(
    const int* __restrict__ src, const int* __restrict__ dst,
    int* __restrict__ cursor, int* __restrict__ src_csr,
    int E, int SE, int N)
{
    int e = blockIdx.x * 256 + threadIdx.x;
    if (e < SE) {
        int s = e / E;
        int pos = atomicAdd(&cursor[(size_t)s * N + dst[e]], 1);
        src_csr[(size_t)s * E + pos] = src[e];
    }
}

// ------------- fused single-pass attention+softmax+gather (fp8 a) ----------
// wave per dst node; 16 lanes/edge, 4 edges per iter. lane fl's 8 features are
// j = i*16+fl (permuted layout). No max pass (|e| <= sum|w|).
__global__ __launch_bounds__(256) void fused_kernel(
    const uint4* __restrict__ feat16, const uint2* __restrict__ a8,
    const uint4* __restrict__ bp16, const float* __restrict__ wout,
    const int* __restrict__ src_csr_all, const int* __restrict__ row_off_all,
    float* __restrict__ out, int N, int S, int E, int k0)
{
    const int by = blockIdx.y, k = k0 + by;
    const int wslot = threadIdx.x >> 6;
    const int node = blockIdx.x * 4 + wslot;
    const int lane = threadIdx.x & 63;
    const int eg = lane >> 4;
    const int fl = lane & 15;
    if (node >= N) return;

    const int* row_off = row_off_all + (size_t)k * (N + 1);
    const int* src_csr = src_csr_all + (size_t)k * E;
    const uint2* a8k  = a8   + (size_t)by * N * 16;
    const uint4* bp16k = bp16 + (size_t)by * N * 16;

    const int beg = row_off[node];
    const int cnt = row_off[node + 1] - beg;
    float* outp = out + (size_t)node * (S * F) + k * F;
    if (cnt == 0) {
        if (eg == 0) {
            *(float4*)(outp + fl * 8)     = make_float4(0.f, 0.f, 0.f, 0.f);
            *(float4*)(outp + fl * 8 + 4) = make_float4(0.f, 0.f, 0.f, 0.f);
        }
        return;
    }

    const float C2  = 2.8853900817779268f;   // 2*log2(e)
    const float L2E = 1.4426950408889634f;

    // permuted per-lane constants: slot i -> feature j = i*16 + fl
    uint4 bv = bp16k[(size_t)node * 16 + fl];
    float bc[8];
    bc[0] = bf_lo(bv.x) * C2; bc[1] = bf_hi(bv.x) * C2;
    bc[2] = bf_lo(bv.y) * C2; bc[3] = bf_hi(bv.y) * C2;
    bc[4] = bf_lo(bv.z) * C2; bc[5] = bf_hi(bv.z) * C2;
    bc[6] = bf_lo(bv.w) * C2; bc[7] = bf_hi(bv.w) * C2;
    const float* wk = wout + (size_t)k * F;
    float wv[8];
    #pragma unroll
    for (int i = 0; i < 8; ++i) wv[i] = wk[i * 16 + fl];

    float sumw = 0.f, sabs = 0.f;
    #pragma unroll
    for (int i = 0; i < 8; ++i) { sumw += wv[i]; sabs += fabsf(wv[i]); }
    #pragma unroll
    for (int off = 1; off < 16; off <<= 1) {
        sumw += __shfl_xor(sumw, off);
        sabs += __shfl_xor(sabs, off);
    }
    const float negswl = -sabs * L2E;   // softmax shift (log2 domain)

    float ssum = 0.f;
    float acc[8] = {0.f, 0.f, 0.f, 0.f, 0.f, 0.f, 0.f, 0.f};
    for (int chunk = 0; chunk < cnt; chunk += 64) {
        int idx = chunk + lane;
        int sv = (idx < cnt) ? src_csr[beg + idx] : 0;
        int cend = min(64, cnt - chunk);
        for (int q = 0; q < cend; q += 4) {
            int my = q + eg;
            int sj = __shfl(sv, my);
            uint2 av8 = a8k[(size_t)sj * 16 + fl];
            uint4 fv  = feat16[(size_t)sj * 16 + fl];
            f32x2 a01 = __builtin_amdgcn_cvt_pk_f32_fp8(av8.x, false);
            f32x2 a23 = __builtin_amdgcn_cvt_pk_f32_fp8(av8.x, true);
            f32x2 a45 = __builtin_amdgcn_cvt_pk_f32_fp8(av8.y, false);
            f32x2 a67 = __builtin_amdgcn_cvt_pk_f32_fp8(av8.y, true);
            float pr;
            pr  = wv[0] * __builtin_amdgcn_rcpf(__builtin_exp2f(fmaf(a01.x, C2, bc[0])) + 1.f);
            pr += wv[1] * __builtin_amdgcn_rcpf(__builtin_exp2f(fmaf(a01.y, C2, bc[1])) + 1.f);
            pr += wv[2] * __builtin_amdgcn_rcpf(__builtin_exp2f(fmaf(a23.x, C2, bc[2])) + 1.f);
            pr += wv[3] * __builtin_amdgcn_rcpf(__builtin_exp2f(fmaf(a23.y, C2, bc[3])) + 1.f);
            pr += wv[4] * __builtin_amdgcn_rcpf(__builtin_exp2f(fmaf(a45.x, C2, bc[4])) + 1.f);
            pr += wv[5] * __builtin_amdgcn_rcpf(__builtin_exp2f(fmaf(a45.y, C2, bc[5])) + 1.f);
            pr += wv[6] * __builtin_amdgcn_rcpf(__builtin_exp2f(fmaf(a67.x, C2, bc[6])) + 1.f);
            pr += wv[7] * __builtin_amdgcn_rcpf(__builtin_exp2f(fmaf(a67.y, C2, bc[7])) + 1.f);
            pr += __shfl_xor(pr, 1);
            pr += __shfl_xor(pr, 2);
            pr += __shfl_xor(pr, 4);
            pr += __shfl_xor(pr, 8);
            float p = sumw - 2.f * pr;                    // edge score e
            float ex = (my < cend) ? __builtin_exp2f(fmaf(p, L2E, negswl)) : 0.f;
            ssum += ex;
            acc[0] = fmaf(ex, bf_lo(fv.x), acc[0]);
            acc[1] = fmaf(ex, bf_hi(fv.x), acc[1]);
            acc[2] = fmaf(ex, bf_lo(fv.y), acc[2]);
            acc[3] = fmaf(ex, bf_hi(fv.y), acc[3]);
            acc[4] = fmaf(ex, bf_lo(fv.z), acc[4]);
            acc[5] = fmaf(ex, bf_hi(fv.z), acc[5]);
            acc[6] = fmaf(ex, bf_lo(fv.w), acc[6]);
            acc[7] = fmaf(ex, bf_hi(fv.w), acc[7]);
        }
    }
    ssum += __shfl_xor(ssum, 16);
    ssum += __shfl_xor(ssum, 32);
    #pragma unroll
    for (int j = 0; j < 8; ++j) {
        acc[j] += __shfl_xor(acc[j], 16);
        acc[j] += __shfl_xor(acc[j], 32);
    }
    float inv = __builtin_amdgcn_rcpf(ssum);
    if (eg == 0) {
        *(float4*)(outp + fl * 8) =
            make_float4(acc[0] * inv, acc[1] * inv, acc[2] * inv, acc[3] * inv);
        *(float4*)(outp + fl * 8 + 4) =
            make_float4(acc[4] * inv, acc[5] * inv, acc[6] * inv, acc[7] * inv);
    }
}

extern "C" void kernel_launch(void* const* d_in, const int* in_sizes, int n_in,
                              void* d_out, int out_size, void* d_ws, size_t ws_size,
                              hipStream_t stream) {
    const float* feat = (const float*)d_in[0];
    const int*   src  = (const int*)d_in[1];
    const int*   dst  = (const int*)d_in[2];
    const float* W    = (const float*)d_in[3];
    const float* bvec = (const float*)d_in[4];
    const float* wout = (const float*)d_in[5];
    float* out = (float*)d_out;

    const int N = in_sizes[0] / F;
    const int S = in_sizes[3] / (2 * F * F);
    const int E = in_sizes[1] / S;
    const int SE = S * E;
    const int BPS = (N + 255) / 256;
    const int NB  = (N + 255) >> 8;
    const int NBS = NB * S;
    const bool packed = (N <= 65536) && (NBS <= 1024) && (S * BPS <= 1024);

    size_t fixed = (size_t)N * 256                // feat16
                 + (size_t)S * 32768 * 2          // Wt
                 + (size_t)SE * 4                 // src_csr
                 + (size_t)SE * 4                 // recs
                 + (size_t)S * N * 4              // cnt
                 + (size_t)S * (N + 1) * 4        // row_off
                 + (size_t)S * BPS * 4 * 2        // partials + scanned
                 + (size_t)(NBS + 1) * 4 * 3;     // bkt_cnt/off/cur
    size_t perB = (size_t)N * 128                 // a8
                + (size_t)N * 256;                // bp16
    const int B = (ws_size >= fixed + perB * (size_t)S + 1024) ? S : 1;

    char* p = (char*)d_ws;
    unsigned* feat16     = (unsigned*)p;        p += (size_t)N * 256;
    unsigned char* a8    = (unsigned char*)p;   p += (size_t)B * N * 128;
    unsigned short* bp16 = (unsigned short*)p;  p += (size_t)B * N * 256;
    unsigned short* Wt   = (unsigned short*)p;  p += (size_t)S * 32768 * 2;
    int*      src_csr  = (int*)p;               p += (size_t)SE * 4;
    unsigned* recs     = (unsigned*)p;          p += (size_t)SE * 4;
    int*      cnt      = (int*)p;               p += (size_t)S * N * 4;
    int*      row_off  = (int*)p;               p += (size_t)S * (N + 1) * 4;
    int*      partials = (int*)p;               p += (size_t)S * BPS * 4;
    int*      scanned  = (int*)p;               p += (size_t)S * BPS * 4;
    int*      bkt_cnt  = (int*)p;               p += (size_t)(NBS + 1) * 4;
    int*      bkt_off  = (int*)p;               p += (size_t)(NBS + 1) * 4;
    int*      bkt_cur  = (int*)p;

    const int n4 = N * F / 4;
    const int proj_blocks = (N + 63) / 64;
    const int node_blocks = (N + 3) / 4;
    const int se_blocks   = (SE + 255) / 256;
    const int wt_total    = S * 256 * 128;

    cvt_feat_kernel<<<2048, 256, 0, stream>>>(feat, feat16, n4);
    cvt_w_kernel<<<(wt_total + 255) / 256, 256, 0, stream>>>(W, Wt, wt_total);

    if (packed) {
        hipMemsetAsync(bkt_cnt, 0, (size_t)NBS * sizeof(int), stream);
        bucket_count_kernel<<<512, 256, 0, stream>>>(dst, bkt_cnt, E, SE, NB, NBS);
        bucket_scan_kernel<<<1, 1024, 0, stream>>>(bkt_cnt, bkt_off, bkt_cur, NBS);
        bucket_scatter_kernel<<<512, 256, 0, stream>>>(src, dst, bkt_cur, recs,
                                                       E, SE, NB, NBS);
        node_count_bucket_kernel<<<NBS, 256, 0, stream>>>(recs, bkt_off, cnt, N, NB);
        partial_kernel<<<dim3(BPS, S), 256, 0, stream>>>(cnt, partials, N, BPS);
        scan_partials_kernel<<<1, 1024, 0, stream>>>(partials, scanned, row_off,
                                                     S, BPS, N);
        emit_kernel<<<dim3(BPS, S), 256, 0, stream>>>(cnt, scanned, row_off, N, BPS);
        csr_fill_bucket_kernel<<<NBS, 256, 0, stream>>>(recs, bkt_off, row_off,
                                                        src_csr, N, E, NB);
    } else {
        hipMemsetAsync(cnt, 0, (size_t)S * N * sizeof(int), stream);
        count_all_kernel<<<se_blocks, 256, 0, stream>>>(dst, cnt, E, SE, N);
        partial_kernel<<<dim3(BPS, S), 256, 0, stream>>>(cnt, partials, N, BPS);
        scan_partials_kernel<<<1, 1024, 0, stream>>>(partials, scanned, row_off,
                                                     S, BPS, N);
        emit_kernel<<<dim3(BPS, S), 256, 0, stream>>>(cnt, scanned, row_off, N, BPS);
        emit_cursor_kernel<<<dim3(BPS, S), 256, 0, stream>>>(row_off, cnt, N);
        fill_all_kernel<<<se_blocks, 256, 0, stream>>>(src, dst, cnt, src_csr,
                                                       E, SE, N);
    }

    for (int k0 = 0; k0 < S; k0 += B) {
        proj_mfma_kernel<<<dim3(proj_blocks, B), 256, 0, stream>>>(
            (const unsigned short*)feat16, Wt, bvec, a8, bp16, N, k0);
        fused_kernel<<<dim3(node_blocks, B), 256, 0, stream>>>(
            (const uint4*)feat16, (const uint2*)a8, (const uint4*)bp16, wout,
            src_csr, row_off, out, N, S, E, k0);
    }
}